// Round 4
// baseline (669.592 us; speedup 1.0000x reference)
//
#include <hip/hip_runtime.h>

#define BB 8
#define CC 256
#define NN 3072

typedef unsigned short u16;
typedef unsigned int   u32;
typedef __attribute__((ext_vector_type(8))) __bf16 bf16x8;
typedef __attribute__((ext_vector_type(8))) u16    u16x8;
typedef __attribute__((ext_vector_type(4))) float  f32x4;

__device__ __forceinline__ float bf2f(u16 u){ u32 x=(u32)u<<16; return __builtin_bit_cast(float,x); }
__device__ __forceinline__ u16 f2bf(float f){ u32 i=__builtin_bit_cast(u32,f); i += 0x7FFFu + ((i>>16)&1u); return (u16)(i>>16); }
__device__ __forceinline__ u32 fkey(float f){ u32 u=__builtin_bit_cast(u32,f); return (u&0x80000000u)? ~u : (u|0x80000000u); }
__device__ __forceinline__ float funkey(u32 k){ u32 u=(k&0x80000000u)? (k^0x80000000u) : ~k; return __builtin_bit_cast(float,u); }

// async global->LDS, 16B per lane. LDS dest wave-uniform; HW adds lane*16.
__device__ __forceinline__ void gl_lds16(const u16* g, u16* l){
  __builtin_amdgcn_global_load_lds((const __attribute__((address_space(1))) void*)g,
                                   (__attribute__((address_space(3))) void*)l, 16, 0, 0);
}

// ---------------- prep: weight split (h,h,l over K'=768); Wq scaled by log2(e) ----------------
__global__ void prep_w(const float* __restrict__ Wq, const float* __restrict__ Wk,
                       const float* __restrict__ Wv, const float* __restrict__ Wt,
                       u16* __restrict__ WarrQ, u16* __restrict__ WarrK,
                       u16* __restrict__ WarrV, u16* __restrict__ WtH){
  int idx = blockIdx.x*256 + threadIdx.x;     // 4*65536
  int p = idx >> 16; int oc = idx & 65535; int o = oc >> 8; int c = oc & 255;
  const float* W = (p==0)?Wq:(p==1)?Wk:(p==2)?Wv:Wt;
  float v = W[oc];
  if(p==0) v *= 1.4426950408889634f;   // energies land in log2 domain -> v_exp_f32 is exp2
  u16 hi = f2bf(v);
  if(p==3){ WtH[oc]=hi; return; }
  u16 lo = f2bf(v - bf2f(hi));
  u16* dst = (p==0)?WarrQ:(p==1)?WarrK:WarrV;
  dst[(size_t)o*768 + c] = hi; dst[(size_t)o*768 + 256 + c] = hi; dst[(size_t)o*768 + 512 + c] = lo;
}

// ---------------- prep: transpose+split x,q -> [b][n][hi 256 | lo 256] ----------------
__global__ void prep_x(const float* __restrict__ x, const float* __restrict__ q,
                       u16* __restrict__ xs, u16* __restrict__ qs){
  int z=blockIdx.z, b=z&7, src=z>>3;
  const float* in = src? q : x;
  u16* outp = src? qs : xs;
  int n0=blockIdx.x*64, c0=blockIdx.y*64;
  __shared__ float t[64][65];
  int tid=threadIdx.x;
  {
    int r=tid>>2, nr=(tid&3)*16;
    const float* base = in + ((size_t)b*CC + c0 + r)*NN + n0 + nr;
    #pragma unroll
    for(int j=0;j<16;j+=4){
      f32x4 v = *(const f32x4*)(base + j);
      t[r][nr+j]=v[0]; t[r][nr+j+1]=v[1]; t[r][nr+j+2]=v[2]; t[r][nr+j+3]=v[3];
    }
  }
  __syncthreads();
  {
    int n=tid>>2, cw=(tid&3)*16;
    u16 hb[16] __attribute__((aligned(16)));
    u16 lb[16] __attribute__((aligned(16)));
    #pragma unroll
    for(int j=0;j<16;j++){
      float v=t[cw+j][n];
      u16 h=f2bf(v); hb[j]=h; lb[j]=f2bf(v-bf2f(h));
    }
    u16* ob = outp + ((size_t)b*NN + n0 + n)*512 + c0 + cw;
    *(u16x8*)(ob)       = *(const u16x8*)(hb);
    *(u16x8*)(ob+8)     = *(const u16x8*)(hb+8);
    *(u16x8*)(ob+256)   = *(const u16x8*)(lb);
    *(u16x8*)(ob+264)   = *(const u16x8*)(lb+8);
  }
}

// ---------------- the GEMM template ----------------
// C[M][N] = A[M][K'] * BT[N][K']^T, 128x128 tile, BK=64, 4 waves, 16x16x32 bf16 MFMA.
// Single-buffered LDS (35KB -> ~4 blocks/CU; implicit multi-block overlap does the
// pipelining -- explicit dbuf measured WORSE, round 3). global_load_lds 16B staging,
// linear LDS dest + source-preswizzled chunk gc = slot ^ (row&7); reads apply the same
// XOR (both-sides-or-neither, rule #21).
// KTT>0: compile-time K-tiles, fully unrolled. KTT==0: runtime KT, identity maps.
template<int AMAP,int BMAP,int EPI,int KTT>
__global__ __launch_bounds__(256,4)
void gemm_k(const u16* __restrict__ A, const u16* __restrict__ BT,
            int lda,int ldbt,long long sA,long long sB,int KT,
            u16* __restrict__ dst, long long sD, int lddst,
            float* __restrict__ dstF,
            const float* __restrict__ bias,
            const float* __restrict__ recl,
            u32* __restrict__ rmax,
            float* __restrict__ rsum,
            float* __restrict__ S1, float* __restrict__ S2,
            const float* __restrict__ qsrc)
{
  __shared__ u16 sm[17664] __attribute__((aligned(16)));   // As 16KB | Bs 16KB | overlay [128][136] | smax 512B
  u16* As = sm; u16* Bs = sm + 8192;
  float* smax = (float*)(sm + 17408);
  const int tid=threadIdx.x, lane=tid&63, wave=tid>>6, wr=wave>>1, wc=wave&1;
  const int nt=blockIdx.x, mt=blockIdx.y, b=blockIdx.z;
  const int lr = lane>>4, lc = lane&15;

  if constexpr (EPI==3){ if(tid<128) smax[tid] = funkey(rmax[(size_t)b*NN + mt*128 + tid]); }

  f32x4 acc[4][4];
  #pragma unroll
  for(int i=0;i<4;i++){
    #pragma unroll
    for(int j=0;j<4;j++){ acc[i][j][0]=0.f; acc[i][j][1]=0.f; acc[i][j][2]=0.f; acc[i][j][3]=0.f; }
  }

  const u16* Ab = A + (size_t)b*sA + (size_t)mt*128*lda;
  const u16* Bb = BT + (size_t)b*sB + (size_t)nt*128*ldbt;

  // hoisted per-lane source pointers (swizzled chunk)
  const u16* Ap[4]; const u16* Bp[4];
  #pragma unroll
  for(int i=0;i<4;i++){
    int f=i*256+tid, row=f>>3, gc=(f&7)^(row&7);
    Ap[i] = Ab + (size_t)row*lda  + gc*8;
    Bp[i] = Bb + (size_t)row*ldbt + gc*8;
  }

  auto stage=[&](int ao,int bo){
    #pragma unroll
    for(int i=0;i<4;i++) gl_lds16(Ap[i]+ao, As + (i*256 + wave*64)*8);
    #pragma unroll
    for(int i=0;i<4;i++) gl_lds16(Bp[i]+bo, Bs + (i*256 + wave*64)*8);
  };
  auto aoff=[&](int kt)->int{ int g=kt>>2,t4=(kt&3)*64;
    return t4 + (AMAP==0? g*256 : (AMAP==1? (g==2?256:0) : (g==1?256:0))); };
  auto boff=[&](int kt)->int{ int g=kt>>2,t4=(kt&3)*64;
    return t4 + (BMAP==0? g*256 : (BMAP==1? (g==2?256:0) : (g==1?256:0))); };
  auto compute=[&](){
    #pragma unroll
    for(int kk=0;kk<2;kk++){
      bf16x8 af[4], bfv[4];
      int c0 = kk*4 + lr;
      #pragma unroll
      for(int i=0;i<4;i++){
        int row = wr*64 + i*16 + lc;
        af[i]  = *(const bf16x8*)(As + (size_t)row*64 + ((c0^(row&7))*8));
      }
      #pragma unroll
      for(int j=0;j<4;j++){
        int row = wc*64 + j*16 + lc;
        bfv[j] = *(const bf16x8*)(Bs + (size_t)row*64 + ((c0^(row&7))*8));
      }
      #pragma unroll
      for(int i=0;i<4;i++){
        #pragma unroll
        for(int j=0;j<4;j++)
          acc[i][j] = __builtin_amdgcn_mfma_f32_16x16x32_bf16(af[i], bfv[j], acc[i][j], 0,0,0);
      }
    }
  };

  if constexpr (KTT>0){
    #pragma unroll
    for(int kt=0;kt<KTT;kt++){
      if(kt) __syncthreads();
      stage(aoff(kt), boff(kt));
      asm volatile("s_waitcnt vmcnt(0)" ::: "memory");
      __syncthreads();
      compute();
    }
  } else {
    int ao = 0;
    for(int kt=0;kt<KT;kt++){
      if(kt) __syncthreads();
      stage(ao, ao);
      asm volatile("s_waitcnt vmcnt(0)" ::: "memory");
      __syncthreads();
      compute();
      ao += 64;
    }
  }

  const int rbase = mt*128 + wr*64;
  const int cbase = nt*128 + wc*64;

  if constexpr (EPI==0){
    // hi/lo split write via LDS coalesce: round 0 = hi, round 1 = lo
    u16* D = dst + (size_t)b*sD;
    u16* Pb = sm;   // [128][136]
    #pragma unroll
    for(int half=0; half<2; ++half){
      __syncthreads();
      #pragma unroll
      for(int i=0;i<4;i++){
        #pragma unroll
        for(int r=0;r<4;r++){
          int rl = wr*64 + i*16 + lr*4 + r;
          #pragma unroll
          for(int j=0;j<4;j++){
            float v = acc[i][j][r];
            u16 h = f2bf(v);
            Pb[rl*136 + wc*64 + j*16 + lc] = half ? f2bf(v - bf2f(h)) : h;
          }
        }
      }
      __syncthreads();
      #pragma unroll
      for(int it=0; it<8; ++it){
        int ch = it*256 + tid, row = ch>>4, ccol=(ch&15)*8;
        *(u16x8*)(D + (size_t)(mt*128+row)*lddst + half*256 + nt*128 + ccol)
            = *(const u16x8*)(Pb + row*136 + ccol);
      }
    }
  } else if constexpr (EPI==1){
    u16* D = dst + (size_t)b*sD;
    #pragma unroll
    for(int i=0;i<4;i++){
      #pragma unroll
      for(int r=0;r<4;r++){
        int row = rbase + i*16 + lr*4 + r;
        float bv_ = bias[row];
        #pragma unroll
        for(int j=0;j<4;j++){
          int col = cbase + j*16 + lc;
          D[(size_t)row*lddst + col] = f2bf(acc[i][j][r] + bv_);
        }
      }
    }
  } else if constexpr (EPI==2){
    #pragma unroll
    for(int i=0;i<4;i++){
      #pragma unroll
      for(int r=0;r<4;r++){
        float mx = acc[i][0][r];
        mx = fmaxf(mx, acc[i][1][r]); mx = fmaxf(mx, acc[i][2][r]); mx = fmaxf(mx, acc[i][3][r]);
        mx = fmaxf(mx, __shfl_xor(mx,1));
        mx = fmaxf(mx, __shfl_xor(mx,2));
        mx = fmaxf(mx, __shfl_xor(mx,4));
        mx = fmaxf(mx, __shfl_xor(mx,8));
        if(lc==0){
          int row = rbase + i*16 + lr*4 + r;
          atomicMax(&rmax[(size_t)b*NN + row], fkey(mx));
        }
      }
    }
  } else if constexpr (EPI==3){
    __syncthreads();
    u16* Pb = sm;   // [128][136] overlay (reads of As/Bs all done)
    #pragma unroll
    for(int i=0;i<4;i++){
      #pragma unroll
      for(int r=0;r<4;r++){
        int rl = wr*64 + i*16 + lr*4 + r;
        float mx = smax[rl];
        float s=0.f;
        #pragma unroll
        for(int j=0;j<4;j++){
          float e2 = acc[i][j][r] - mx;   // log2-domain
          float p;
          asm("v_exp_f32 %0, %1" : "=v"(p) : "v"(e2));
          s+=p;
          Pb[rl*136 + wc*64 + j*16 + lc] = f2bf(p);
        }
        s += __shfl_xor(s,1); s += __shfl_xor(s,2); s += __shfl_xor(s,4); s += __shfl_xor(s,8);
        if(lc==0) atomicAdd(&rsum[(size_t)b*NN + mt*128 + rl], s);
      }
    }
    __syncthreads();
    u16* D = dst + (size_t)b*sD;
    #pragma unroll
    for(int it=0; it<8; ++it){
      int ch = it*256 + tid, row = ch>>4, ccol=(ch&15)*8;
      *(u16x8*)(D + (size_t)(mt*128+row)*lddst + nt*128 + ccol) = *(const u16x8*)(Pb + row*136 + ccol);
    }
  } else if constexpr (EPI==4){
    const float* rl_ = recl + (size_t)b*NN;
    const u16* qs_b  = (const u16*)qsrc + (size_t)b*NN*512;   // q split [n][hi|lo]
    u16* D = dst + (size_t)b*sD;
    #pragma unroll
    for(int i=0;i<4;i++){
      int nb = rbase + i*16 + lr*4;
      float rc[4];
      #pragma unroll
      for(int r=0;r<4;r++) rc[r] = rl_[nb+r];
      #pragma unroll
      for(int j=0;j<4;j++){
        int c_ = cbase + j*16 + lc;
        #pragma unroll
        for(int r=0;r<4;r++){
          const u16* qr = qs_b + (size_t)(nb+r)*512 + c_;
          float qv = bf2f(qr[0]) + bf2f(qr[256]);
          float dq = qv - acc[i][j][r]*rc[r];
          D[(size_t)(nb+r)*lddst + c_] = f2bf(dq);
        }
      }
    }
  } else if constexpr (EPI==5){
    float* Df = dstF + (size_t)b*CC*NN;
    #pragma unroll
    for(int i=0;i<4;i++){
      #pragma unroll
      for(int r=0;r<4;r++){
        int row = rbase + i*16 + lr*4 + r;
        float bt_ = bias[row];
        float s=0.f, s2=0.f;
        #pragma unroll
        for(int j=0;j<4;j++){
          int col = cbase + j*16 + lc;
          float v = acc[i][j][r] + bt_;
          Df[(size_t)row*NN + col] = v;
          s += v; s2 += v*v;
        }
        s  += __shfl_xor(s,1);  s  += __shfl_xor(s,2);  s  += __shfl_xor(s,4);  s  += __shfl_xor(s,8);
        s2 += __shfl_xor(s2,1); s2 += __shfl_xor(s2,2); s2 += __shfl_xor(s2,4); s2 += __shfl_xor(s2,8);
        if(lc==0){ atomicAdd(&S1[row], s); atomicAdd(&S2[row], s2); }
      }
    }
  }
}

// ---------------- small kernels ----------------
__global__ void recl_k(const float* __restrict__ l, float* __restrict__ recl){
  int i = blockIdx.x*256 + threadIdx.x;  // 24576
  recl[i] = 1.0f / l[i];
}

// colsum[m] = sum_n P[n][m] * recl[n], vectorized 8 cols / thread (16B loads)
__global__ void colsum_k(const u16* __restrict__ P, const float* __restrict__ recl,
                         float* __restrict__ colsum){
  int b = blockIdx.z;
  int m0 = blockIdx.x*1024 + threadIdx.x*8;  // gridDim.x=3, blockDim=128
  int n0 = blockIdx.y*48;                    // gridDim.y=64
  const u16* Pb = P + (size_t)b*NN*NN;
  const float* rb = recl + (size_t)b*NN;
  float acc[8] = {0,0,0,0,0,0,0,0};
  for(int i=0;i<48;i++){
    int n = n0+i;
    u16x8 v = *(const u16x8*)(Pb + (size_t)n*NN + m0);
    float r = rb[n];
    #pragma unroll
    for(int j=0;j<8;j++) acc[j] += bf2f(v[j]) * r;
  }
  float* cb = colsum + (size_t)b*NN + m0;
  #pragma unroll
  for(int j=0;j<8;j++) atomicAdd(&cb[j], acc[j]);
}

__global__ void vprime_k(const u16* __restrict__ XV, const float* __restrict__ colsum,
                         u16* __restrict__ VpT){
  size_t base = ((size_t)blockIdx.x*256 + threadIdx.x)*8;   // grid 3072
  int m = (int)(base % NN);
  int b = (int)(base / ((size_t)NN*CC));
  const float* cs = colsum + (size_t)b*NN + m;
  u16x8 v = *(const u16x8*)(XV + base);
  u16x8 o;
  #pragma unroll
  for(int j=0;j<8;j++) o[j] = f2bf(bf2f(v[j]) / (1e-9f + cs[j]));
  *(u16x8*)(VpT + base) = o;
}

__global__ void bnfin_k(const float* __restrict__ S1, const float* __restrict__ S2,
                        const float* __restrict__ gamma, const float* __restrict__ beta,
                        float* __restrict__ scale, float* __restrict__ shift){
  int c = threadIdx.x;
  float cnt = (float)(BB*NN);
  float mean = S1[c]/cnt;
  float var  = S2[c]/cnt - mean*mean;
  float rs = rsqrtf(var + 1e-5f);
  float sc = gamma[c]*rs;
  scale[c] = sc;
  shift[c] = beta[c] - mean*sc;
}

__global__ void outk(const float* __restrict__ T, const float* __restrict__ q,
                     const float* __restrict__ scale, const float* __restrict__ shift,
                     float* __restrict__ out){
  size_t i4 = (size_t)blockIdx.x*256 + threadIdx.x;    // 1,572,864 float4's
  int c = (int)((i4 / 768) & 255);
  f32x4 tv = *(const f32x4*)(T + i4*4);
  f32x4 qv = *(const f32x4*)(q + i4*4);
  float sc = scale[c], sh = shift[c];
  f32x4 o;
  #pragma unroll
  for(int k=0;k<4;k++){
    float h = tv[k]*sc + sh;
    o[k] = qv[k] + (h>0.f? h : 0.f);
  }
  *(f32x4*)(out + i4*4) = o;
}

// ---------------- launcher ----------------
extern "C" void kernel_launch(void* const* d_in, const int* in_sizes, int n_in,
                              void* d_out, int out_size, void* d_ws, size_t ws_size,
                              hipStream_t stream)
{
  const float* x  = (const float*)d_in[0];
  const float* q  = (const float*)d_in[1];
  const float* Wq = (const float*)d_in[2];
  const float* Wk = (const float*)d_in[3];
  const float* Wv = (const float*)d_in[4];
  const float* bv = (const float*)d_in[5];
  const float* Wt = (const float*)d_in[6];
  const float* bt = (const float*)d_in[7];
  const float* gamma=(const float*)d_in[8];
  const float* beta =(const float*)d_in[9];
  float* out = (float*)d_out;
  char* ws = (char*)d_ws;

  u16* P    = (u16*)(ws + 0);            // 150,994,944
  u16* XQ   = (u16*)(ws + 150994944);    // 25,165,824  (VpT aliases after vprime)
  u16* XK   = (u16*)(ws + 176160768);    // 25,165,824
  u16* QS   = (u16*)(ws + 201326592);    // 25,165,824  (T aliases after PV)
  u16* XS   = (u16*)(ws + 226492416);    // 25,165,824  (DQ aliases after PV)
  u16* XV   = (u16*)(ws + 251658240);    // 12,582,912
  u16* WarrQ= (u16*)(ws + 264241152);
  u16* WarrK= (u16*)(ws + 264634368);
  u16* WarrV= (u16*)(ws + 265027584);
  u16* WtH  = (u16*)(ws + 265420800);
  u32* rmax = (u32*)(ws + 265551872);
  float* l  = (float*)(ws + 265551872 + 98304);
  float* colsum=(float*)(ws + 265551872 + 196608);
  float* S1 = (float*)(ws + 265551872 + 294912);
  float* S2 = (float*)(ws + 265551872 + 295936);
  float* recl = (float*)(ws + 265848832);
  float* scale= (float*)(ws + 265947136);
  float* shift= (float*)(ws + 265948160);
  u16* VpT = XQ;
  float* T = (float*)QS;
  u16* DQ  = XS;

  hipMemsetAsync(ws + 265551872, 0, 296960, stream);

  prep_w<<<1024,256,0,stream>>>(Wq,Wk,Wv,Wt,WarrQ,WarrK,WarrV,WtH);
  prep_x<<<dim3(48,4,16),256,0,stream>>>(x,q,XS,QS);

  // x_q = (log2e*Wq)*q (split K'=768) -> XQ[n][hi|lo]
  gemm_k<2,0,0,12><<<dim3(2,24,8),256,0,stream>>>(QS, WarrQ, 512, 768, (long long)NN*512, 0, 12,
      XQ, (long long)NN*512, 512, nullptr, nullptr, nullptr, nullptr, nullptr, nullptr, nullptr, nullptr);
  // x_k = Wk*x -> XK[m][hi|lo]
  gemm_k<2,0,0,12><<<dim3(2,24,8),256,0,stream>>>(XS, WarrK, 512, 768, (long long)NN*512, 0, 12,
      XK, (long long)NN*512, 512, nullptr, nullptr, nullptr, nullptr, nullptr, nullptr, nullptr, nullptr);
  // x_v = Wv*x + bv -> XV[c][m]
  gemm_k<0,2,1,12><<<dim3(24,2,8),256,0,stream>>>(WarrV, XS, 768, 512, 0, (long long)NN*512, 12,
      XV, (long long)CC*NN, NN, nullptr, bv, nullptr, nullptr, nullptr, nullptr, nullptr, nullptr);
  // approx rowmax (hi*hi only, first 768 columns; underestimate-safe shift)
  gemm_k<0,0,2,4><<<dim3(6,24,8),256,0,stream>>>(XQ, XK, 512, 512, (long long)NN*512, (long long)NN*512, 4,
      nullptr, 0, 0, nullptr, nullptr, nullptr, rmax, nullptr, nullptr, nullptr, nullptr);
  // split energy -> P = exp2(e2 - m2), rowsums l
  gemm_k<1,2,3,12><<<dim3(24,24,8),256,0,stream>>>(XQ, XK, 512, 512, (long long)NN*512, (long long)NN*512, 12,
      P, (long long)NN*NN, NN, nullptr, nullptr, nullptr, rmax, l, nullptr, nullptr, nullptr);
  recl_k<<<96,256,0,stream>>>(l, recl);
  colsum_k<<<dim3(3,64,8),128,0,stream>>>(P, recl, colsum);
  vprime_k<<<3072,256,0,stream>>>(XV, colsum, VpT);
  // x_r^T, fused dq = q - x_r -> DQ[n][c]   (q read from split QS)
  gemm_k<0,0,4,0><<<dim3(2,24,8),256,0,stream>>>(P, VpT, NN, NN, (long long)NN*NN, (long long)CC*NN, 48,
      DQ, (long long)NN*CC, CC, nullptr, nullptr, recl, nullptr, nullptr, nullptr, nullptr, (const float*)QS);
  // t = Wt*dq + bt -> T[o][n] f32, + BN partial sums
  gemm_k<0,0,5,4><<<dim3(24,2,8),256,0,stream>>>(WtH, DQ, 256, 256, 0, (long long)NN*CC, 4,
      nullptr, 0, 0, T, bt, nullptr, nullptr, nullptr, S1, S2, nullptr);
  bnfin_k<<<1,256,0,stream>>>(S1,S2,gamma,beta,scale,shift);
  outk<<<6144,256,0,stream>>>(T,q,scale,shift,out);
}

// Round 5
// 586.284 us; speedup vs baseline: 1.1421x; 1.1421x over previous
//
#include <hip/hip_runtime.h>

#define BB 8
#define CC 256
#define NN 3072

typedef unsigned short u16;
typedef unsigned int   u32;
typedef __attribute__((ext_vector_type(8))) __bf16 bf16x8;
typedef __attribute__((ext_vector_type(8))) u16    u16x8;
typedef __attribute__((ext_vector_type(4))) float  f32x4;

__device__ __forceinline__ float bf2f(u16 u){ u32 x=(u32)u<<16; return __builtin_bit_cast(float,x); }
__device__ __forceinline__ u16 f2bf(float f){ u32 i=__builtin_bit_cast(u32,f); i += 0x7FFFu + ((i>>16)&1u); return (u16)(i>>16); }
__device__ __forceinline__ u32 fkey(float f){ u32 u=__builtin_bit_cast(u32,f); return (u&0x80000000u)? ~u : (u|0x80000000u); }
__device__ __forceinline__ float funkey(u32 k){ u32 u=(k&0x80000000u)? (k^0x80000000u) : ~k; return __builtin_bit_cast(float,u); }

// async global->LDS, 16B per lane. LDS dest wave-uniform; HW adds lane*16.
__device__ __forceinline__ void gl_lds16(const u16* g, u16* l){
  __builtin_amdgcn_global_load_lds((const __attribute__((address_space(1))) void*)g,
                                   (__attribute__((address_space(3))) void*)l, 16, 0, 0);
}

// ---------------- prep: weight split (h,h,l over K'=768); Wq scaled by log2(e) ----------------
__global__ void prep_w(const float* __restrict__ Wq, const float* __restrict__ Wk,
                       const float* __restrict__ Wv, const float* __restrict__ Wt,
                       u16* __restrict__ WarrQ, u16* __restrict__ WarrK,
                       u16* __restrict__ WarrV, u16* __restrict__ WtH){
  int idx = blockIdx.x*256 + threadIdx.x;     // 4*65536
  int p = idx >> 16; int oc = idx & 65535; int o = oc >> 8; int c = oc & 255;
  const float* W = (p==0)?Wq:(p==1)?Wk:(p==2)?Wv:Wt;
  float v = W[oc];
  if(p==0) v *= 1.4426950408889634f;   // energies land in log2 domain -> v_exp_f32 is exp2
  u16 hi = f2bf(v);
  if(p==3){ WtH[oc]=hi; return; }
  u16 lo = f2bf(v - bf2f(hi));
  u16* dst = (p==0)?WarrQ:(p==1)?WarrK:WarrV;
  dst[(size_t)o*768 + c] = hi; dst[(size_t)o*768 + 256 + c] = hi; dst[(size_t)o*768 + 512 + c] = lo;
}

// ---------------- prep: transpose+split x,q -> [b][n][hi 256 | lo 256] ----------------
__global__ void prep_x(const float* __restrict__ x, const float* __restrict__ q,
                       u16* __restrict__ xs, u16* __restrict__ qs){
  int z=blockIdx.z, b=z&7, src=z>>3;
  const float* in = src? q : x;
  u16* outp = src? qs : xs;
  int n0=blockIdx.x*64, c0=blockIdx.y*64;
  __shared__ float t[64][65];
  int tid=threadIdx.x;
  {
    int r=tid>>2, nr=(tid&3)*16;
    const float* base = in + ((size_t)b*CC + c0 + r)*NN + n0 + nr;
    #pragma unroll
    for(int j=0;j<16;j+=4){
      f32x4 v = *(const f32x4*)(base + j);
      t[r][nr+j]=v[0]; t[r][nr+j+1]=v[1]; t[r][nr+j+2]=v[2]; t[r][nr+j+3]=v[3];
    }
  }
  __syncthreads();
  {
    int n=tid>>2, cw=(tid&3)*16;
    u16 hb[16] __attribute__((aligned(16)));
    u16 lb[16] __attribute__((aligned(16)));
    #pragma unroll
    for(int j=0;j<16;j++){
      float v=t[cw+j][n];
      u16 h=f2bf(v); hb[j]=h; lb[j]=f2bf(v-bf2f(h));
    }
    u16* ob = outp + ((size_t)b*NN + n0 + n)*512 + c0 + cw;
    *(u16x8*)(ob)       = *(const u16x8*)(hb);
    *(u16x8*)(ob+8)     = *(const u16x8*)(hb+8);
    *(u16x8*)(ob+256)   = *(const u16x8*)(lb);
    *(u16x8*)(ob+264)   = *(const u16x8*)(lb+8);
  }
}

// ---------------- the GEMM template ----------------
// C[M][N] = A[M][K'] * BT[N][K']^T, BK=64, 4 waves (2x2), 16x16x32 bf16 MFMA.
// Tile = 128 x (NW*32): NW=4 -> 128x128 (64x64/wave), NW=8 -> 128x256 (64x128/wave).
// Single-buffered LDS; __launch_bounds__(256,2) -- bounds(256,4) spilled (round 4),
// explicit dbuf regressed (round 3). global_load_lds 16B staging, linear LDS dest +
// source-preswizzled chunk gc = slot ^ (row&7); reads apply the same XOR (rule #21).
// KTT>0: compile-time K-tiles, fully unrolled. KTT==0: runtime KT, identity maps.
template<int AMAP,int BMAP,int EPI,int KTT,int NW>
__global__ __launch_bounds__(256,2)
void gemm_k(const u16* __restrict__ A, const u16* __restrict__ BT,
            int lda,int ldbt,long long sA,long long sB,int KT,
            u16* __restrict__ dst, long long sD, int lddst,
            float* __restrict__ dstF,
            const float* __restrict__ bias,
            const float* __restrict__ recl,
            u32* __restrict__ rmax,
            float* __restrict__ rsum,
            float* __restrict__ S1, float* __restrict__ S2,
            const float* __restrict__ qsrc)
{
  constexpr int BROWS = 2*NW*16;                       // B-tile rows (= C cols)
  constexpr int CORE  = 8192 + BROWS*64;               // As + Bs in u16
  constexpr int SMSZ  = (CORE > 17408 ? CORE : 17408) + 256;
  __shared__ u16 sm[SMSZ] __attribute__((aligned(16)));
  u16* As = sm; u16* Bs = sm + 8192;
  float* smax = (float*)(sm + SMSZ - 256);
  const int tid=threadIdx.x, lane=tid&63, wave=tid>>6, wr=wave>>1, wc=wave&1;
  const int nt=blockIdx.x, mt=blockIdx.y, b=blockIdx.z;
  const int lr = lane>>4, lc = lane&15;

  if constexpr (EPI==3){ if(tid<128) smax[tid] = funkey(rmax[(size_t)b*NN + mt*128 + tid]); }

  f32x4 acc[4][NW];
  #pragma unroll
  for(int i=0;i<4;i++){
    #pragma unroll
    for(int j=0;j<NW;j++){ acc[i][j][0]=0.f; acc[i][j][1]=0.f; acc[i][j][2]=0.f; acc[i][j][3]=0.f; }
  }

  const u16* Ab = A + (size_t)b*sA + (size_t)mt*128*lda;
  const u16* Bb = BT + (size_t)b*sB + (size_t)nt*BROWS*ldbt;

  // hoisted per-lane source pointers (swizzled chunk)
  const u16* Ap[4]; const u16* Bp[BROWS/32];
  #pragma unroll
  for(int i=0;i<4;i++){
    int f=i*256+tid, row=f>>3, gc=(f&7)^(row&7);
    Ap[i] = Ab + (size_t)row*lda  + gc*8;
  }
  #pragma unroll
  for(int i=0;i<BROWS/32;i++){
    int f=i*256+tid, row=f>>3, gc=(f&7)^(row&7);
    Bp[i] = Bb + (size_t)row*ldbt + gc*8;
  }

  auto stage=[&](int ao,int bo){
    #pragma unroll
    for(int i=0;i<4;i++) gl_lds16(Ap[i]+ao, As + (i*256 + wave*64)*8);
    #pragma unroll
    for(int i=0;i<BROWS/32;i++) gl_lds16(Bp[i]+bo, Bs + (i*256 + wave*64)*8);
  };
  auto aoff=[&](int kt)->int{ int g=kt>>2,t4=(kt&3)*64;
    return t4 + (AMAP==0? g*256 : (AMAP==1? (g==2?256:0) : (g==1?256:0))); };
  auto boff=[&](int kt)->int{ int g=kt>>2,t4=(kt&3)*64;
    return t4 + (BMAP==0? g*256 : (BMAP==1? (g==2?256:0) : (g==1?256:0))); };
  auto compute=[&](){
    #pragma unroll
    for(int kk=0;kk<2;kk++){
      bf16x8 af[4], bfv[NW];
      int c0 = kk*4 + lr;
      #pragma unroll
      for(int i=0;i<4;i++){
        int row = wr*64 + i*16 + lc;
        af[i]  = *(const bf16x8*)(As + (size_t)row*64 + ((c0^(row&7))*8));
      }
      #pragma unroll
      for(int j=0;j<NW;j++){
        int row = wc*(NW*16) + j*16 + lc;
        bfv[j] = *(const bf16x8*)(Bs + (size_t)row*64 + ((c0^(row&7))*8));
      }
      #pragma unroll
      for(int i=0;i<4;i++){
        #pragma unroll
        for(int j=0;j<NW;j++)
          acc[i][j] = __builtin_amdgcn_mfma_f32_16x16x32_bf16(af[i], bfv[j], acc[i][j], 0,0,0);
      }
    }
  };

  if constexpr (KTT>0){
    #pragma unroll
    for(int kt=0;kt<KTT;kt++){
      if(kt) __syncthreads();
      stage(aoff(kt), boff(kt));
      asm volatile("s_waitcnt vmcnt(0)" ::: "memory");
      __syncthreads();
      compute();
    }
  } else {
    int ao = 0;
    for(int kt=0;kt<KT;kt++){
      if(kt) __syncthreads();
      stage(ao, ao);
      asm volatile("s_waitcnt vmcnt(0)" ::: "memory");
      __syncthreads();
      compute();
      ao += 64;
    }
  }

  const int rbase = mt*128 + wr*64;
  const int cbase = nt*BROWS + wc*(NW*16);

  if constexpr (EPI==0){
    // hi/lo split write via LDS coalesce: round 0 = hi, round 1 = lo
    u16* D = dst + (size_t)b*sD;
    u16* Pb = sm;   // [128][136]
    #pragma unroll
    for(int half=0; half<2; ++half){
      __syncthreads();
      #pragma unroll
      for(int i=0;i<4;i++){
        #pragma unroll
        for(int r=0;r<4;r++){
          int rl = wr*64 + i*16 + lr*4 + r;
          #pragma unroll
          for(int j=0;j<NW;j++){
            float v = acc[i][j][r];
            u16 h = f2bf(v);
            Pb[rl*136 + wc*(NW*16) + j*16 + lc] = half ? f2bf(v - bf2f(h)) : h;
          }
        }
      }
      __syncthreads();
      #pragma unroll
      for(int it=0; it<8; ++it){
        int ch = it*256 + tid, row = ch>>4, ccol=(ch&15)*8;
        *(u16x8*)(D + (size_t)(mt*128+row)*lddst + half*256 + nt*128 + ccol)
            = *(const u16x8*)(Pb + row*136 + ccol);
      }
    }
  } else if constexpr (EPI==1){
    u16* D = dst + (size_t)b*sD;
    #pragma unroll
    for(int i=0;i<4;i++){
      #pragma unroll
      for(int r=0;r<4;r++){
        int row = rbase + i*16 + lr*4 + r;
        float bv_ = bias[row];
        #pragma unroll
        for(int j=0;j<NW;j++){
          int col = cbase + j*16 + lc;
          D[(size_t)row*lddst + col] = f2bf(acc[i][j][r] + bv_);
        }
      }
    }
  } else if constexpr (EPI==2){
    #pragma unroll
    for(int i=0;i<4;i++){
      #pragma unroll
      for(int r=0;r<4;r++){
        float mx = acc[i][0][r];
        #pragma unroll
        for(int j=1;j<NW;j++) mx = fmaxf(mx, acc[i][j][r]);
        mx = fmaxf(mx, __shfl_xor(mx,1));
        mx = fmaxf(mx, __shfl_xor(mx,2));
        mx = fmaxf(mx, __shfl_xor(mx,4));
        mx = fmaxf(mx, __shfl_xor(mx,8));
        if(lc==0){
          int row = rbase + i*16 + lr*4 + r;
          atomicMax(&rmax[(size_t)b*NN + row], fkey(mx));
        }
      }
    }
  } else if constexpr (EPI==3){
    __syncthreads();
    u16* Pb = sm;   // [128][136] overlay (reads of As/Bs all done)
    #pragma unroll
    for(int i=0;i<4;i++){
      #pragma unroll
      for(int r=0;r<4;r++){
        int rl = wr*64 + i*16 + lr*4 + r;
        float mx = smax[rl];
        float s=0.f;
        #pragma unroll
        for(int j=0;j<NW;j++){
          float e2 = acc[i][j][r] - mx;   // log2-domain
          float p;
          asm("v_exp_f32 %0, %1" : "=v"(p) : "v"(e2));
          s+=p;
          Pb[rl*136 + wc*(NW*16) + j*16 + lc] = f2bf(p);
        }
        s += __shfl_xor(s,1); s += __shfl_xor(s,2); s += __shfl_xor(s,4); s += __shfl_xor(s,8);
        if(lc==0) atomicAdd(&rsum[(size_t)b*NN + mt*128 + rl], s);
      }
    }
    __syncthreads();
    u16* D = dst + (size_t)b*sD;
    #pragma unroll
    for(int it=0; it<8; ++it){
      int ch = it*256 + tid, row = ch>>4, ccol=(ch&15)*8;
      *(u16x8*)(D + (size_t)(mt*128+row)*lddst + nt*128 + ccol) = *(const u16x8*)(Pb + row*136 + ccol);
    }
  } else if constexpr (EPI==4){
    const float* rl_ = recl + (size_t)b*NN;
    const u16* qs_b  = (const u16*)qsrc + (size_t)b*NN*512;   // q split [n][hi|lo]
    u16* D = dst + (size_t)b*sD;
    #pragma unroll
    for(int i=0;i<4;i++){
      int nb = rbase + i*16 + lr*4;
      float rc[4];
      #pragma unroll
      for(int r=0;r<4;r++) rc[r] = rl_[nb+r];
      #pragma unroll
      for(int j=0;j<NW;j++){
        int c_ = cbase + j*16 + lc;
        #pragma unroll
        for(int r=0;r<4;r++){
          const u16* qr = qs_b + (size_t)(nb+r)*512 + c_;
          float qv = bf2f(qr[0]) + bf2f(qr[256]);
          float dq = qv - acc[i][j][r]*rc[r];
          D[(size_t)(nb+r)*lddst + c_] = f2bf(dq);
        }
      }
    }
  } else if constexpr (EPI==5){
    float* Df = dstF + (size_t)b*CC*NN;
    #pragma unroll
    for(int i=0;i<4;i++){
      #pragma unroll
      for(int r=0;r<4;r++){
        int row = rbase + i*16 + lr*4 + r;
        float bt_ = bias[row];
        float s=0.f, s2=0.f;
        #pragma unroll
        for(int j=0;j<NW;j++){
          int col = cbase + j*16 + lc;
          float v = acc[i][j][r] + bt_;
          Df[(size_t)row*NN + col] = v;
          s += v; s2 += v*v;
        }
        s  += __shfl_xor(s,1);  s  += __shfl_xor(s,2);  s  += __shfl_xor(s,4);  s  += __shfl_xor(s,8);
        s2 += __shfl_xor(s2,1); s2 += __shfl_xor(s2,2); s2 += __shfl_xor(s2,4); s2 += __shfl_xor(s2,8);
        if(lc==0){ atomicAdd(&S1[row], s); atomicAdd(&S2[row], s2); }
      }
    }
  }
}

// ---------------- small kernels ----------------
__global__ void recl_k(const float* __restrict__ l, float* __restrict__ recl){
  int i = blockIdx.x*256 + threadIdx.x;  // 24576
  recl[i] = 1.0f / l[i];
}

// colsum[m] = sum_n P[n][m] * recl[n], vectorized 8 cols / thread (16B loads)
__global__ void colsum_k(const u16* __restrict__ P, const float* __restrict__ recl,
                         float* __restrict__ colsum){
  int b = blockIdx.z;
  int m0 = blockIdx.x*1024 + threadIdx.x*8;  // gridDim.x=3, blockDim=128
  int n0 = blockIdx.y*48;                    // gridDim.y=64
  const u16* Pb = P + (size_t)b*NN*NN;
  const float* rb = recl + (size_t)b*NN;
  float acc[8] = {0,0,0,0,0,0,0,0};
  for(int i=0;i<48;i++){
    int n = n0+i;
    u16x8 v = *(const u16x8*)(Pb + (size_t)n*NN + m0);
    float r = rb[n];
    #pragma unroll
    for(int j=0;j<8;j++) acc[j] += bf2f(v[j]) * r;
  }
  float* cb = colsum + (size_t)b*NN + m0;
  #pragma unroll
  for(int j=0;j<8;j++) atomicAdd(&cb[j], acc[j]);
}

__global__ void vprime_k(const u16* __restrict__ XV, const float* __restrict__ colsum,
                         u16* __restrict__ VpT){
  size_t base = ((size_t)blockIdx.x*256 + threadIdx.x)*8;   // grid 3072
  int m = (int)(base % NN);
  int b = (int)(base / ((size_t)NN*CC));
  const float* cs = colsum + (size_t)b*NN + m;
  u16x8 v = *(const u16x8*)(XV + base);
  u16x8 o;
  #pragma unroll
  for(int j=0;j<8;j++) o[j] = f2bf(bf2f(v[j]) / (1e-9f + cs[j]));
  *(u16x8*)(VpT + base) = o;
}

__global__ void bnfin_k(const float* __restrict__ S1, const float* __restrict__ S2,
                        const float* __restrict__ gamma, const float* __restrict__ beta,
                        float* __restrict__ scale, float* __restrict__ shift){
  int c = threadIdx.x;
  float cnt = (float)(BB*NN);
  float mean = S1[c]/cnt;
  float var  = S2[c]/cnt - mean*mean;
  float rs = rsqrtf(var + 1e-5f);
  float sc = gamma[c]*rs;
  scale[c] = sc;
  shift[c] = beta[c] - mean*sc;
}

__global__ void outk(const float* __restrict__ T, const float* __restrict__ q,
                     const float* __restrict__ scale, const float* __restrict__ shift,
                     float* __restrict__ out){
  size_t i4 = (size_t)blockIdx.x*256 + threadIdx.x;    // 1,572,864 float4's
  int c = (int)((i4 / 768) & 255);
  f32x4 tv = *(const f32x4*)(T + i4*4);
  f32x4 qv = *(const f32x4*)(q + i4*4);
  float sc = scale[c], sh = shift[c];
  f32x4 o;
  #pragma unroll
  for(int k=0;k<4;k++){
    float h = tv[k]*sc + sh;
    o[k] = qv[k] + (h>0.f? h : 0.f);
  }
  *(f32x4*)(out + i4*4) = o;
}

// ---------------- launcher ----------------
extern "C" void kernel_launch(void* const* d_in, const int* in_sizes, int n_in,
                              void* d_out, int out_size, void* d_ws, size_t ws_size,
                              hipStream_t stream)
{
  const float* x  = (const float*)d_in[0];
  const float* q  = (const float*)d_in[1];
  const float* Wq = (const float*)d_in[2];
  const float* Wk = (const float*)d_in[3];
  const float* Wv = (const float*)d_in[4];
  const float* bv = (const float*)d_in[5];
  const float* Wt = (const float*)d_in[6];
  const float* bt = (const float*)d_in[7];
  const float* gamma=(const float*)d_in[8];
  const float* beta =(const float*)d_in[9];
  float* out = (float*)d_out;
  char* ws = (char*)d_ws;

  u16* P    = (u16*)(ws + 0);            // 150,994,944
  u16* XQ   = (u16*)(ws + 150994944);    // 25,165,824  (VpT aliases after vprime)
  u16* XK   = (u16*)(ws + 176160768);    // 25,165,824
  u16* QS   = (u16*)(ws + 201326592);    // 25,165,824  (T aliases after PV)
  u16* XS   = (u16*)(ws + 226492416);    // 25,165,824  (DQ aliases after PV)
  u16* XV   = (u16*)(ws + 251658240);    // 12,582,912
  u16* WarrQ= (u16*)(ws + 264241152);
  u16* WarrK= (u16*)(ws + 264634368);
  u16* WarrV= (u16*)(ws + 265027584);
  u16* WtH  = (u16*)(ws + 265420800);
  u32* rmax = (u32*)(ws + 265551872);
  float* l  = (float*)(ws + 265551872 + 98304);
  float* colsum=(float*)(ws + 265551872 + 196608);
  float* S1 = (float*)(ws + 265551872 + 294912);
  float* S2 = (float*)(ws + 265551872 + 295936);
  float* recl = (float*)(ws + 265848832);
  float* scale= (float*)(ws + 265947136);
  float* shift= (float*)(ws + 265948160);
  u16* VpT = XQ;
  float* T = (float*)QS;
  u16* DQ  = XS;

  hipMemsetAsync(ws + 265551872, 0, 296960, stream);

  prep_w<<<1024,256,0,stream>>>(Wq,Wk,Wv,Wt,WarrQ,WarrK,WarrV,WtH);
  prep_x<<<dim3(48,4,16),256,0,stream>>>(x,q,XS,QS);

  // x_q = (log2e*Wq)*q (split K'=768) -> XQ[n][hi|lo]
  gemm_k<2,0,0,12,4><<<dim3(2,24,8),256,0,stream>>>(QS, WarrQ, 512, 768, (long long)NN*512, 0, 12,
      XQ, (long long)NN*512, 512, nullptr, nullptr, nullptr, nullptr, nullptr, nullptr, nullptr, nullptr);
  // x_k = Wk*x -> XK[m][hi|lo]
  gemm_k<2,0,0,12,4><<<dim3(2,24,8),256,0,stream>>>(XS, WarrK, 512, 768, (long long)NN*512, 0, 12,
      XK, (long long)NN*512, 512, nullptr, nullptr, nullptr, nullptr, nullptr, nullptr, nullptr, nullptr);
  // x_v = Wv*x + bv -> XV[c][m]
  gemm_k<0,2,1,12,4><<<dim3(24,2,8),256,0,stream>>>(WarrV, XS, 768, 512, 0, (long long)NN*512, 12,
      XV, (long long)CC*NN, NN, nullptr, bv, nullptr, nullptr, nullptr, nullptr, nullptr, nullptr);
  // approx rowmax (hi*hi only, first 768 columns; underestimate-safe shift)
  gemm_k<0,0,2,4,4><<<dim3(6,24,8),256,0,stream>>>(XQ, XK, 512, 512, (long long)NN*512, (long long)NN*512, 4,
      nullptr, 0, 0, nullptr, nullptr, nullptr, rmax, nullptr, nullptr, nullptr, nullptr);
  // split energy -> P = exp2(e2 - m2), rowsums l
  gemm_k<1,2,3,12,4><<<dim3(24,24,8),256,0,stream>>>(XQ, XK, 512, 512, (long long)NN*512, (long long)NN*512, 12,
      P, (long long)NN*NN, NN, nullptr, nullptr, nullptr, rmax, l, nullptr, nullptr, nullptr);
  recl_k<<<96,256,0,stream>>>(l, recl);
  colsum_k<<<dim3(3,64,8),128,0,stream>>>(P, recl, colsum);
  vprime_k<<<3072,256,0,stream>>>(XV, colsum, VpT);
  // x_r^T, fused dq = q - x_r -> DQ[n][c]   (q read from split QS; 128x256 tile, P read once)
  gemm_k<0,0,4,0,8><<<dim3(1,24,8),256,0,stream>>>(P, VpT, NN, NN, (long long)NN*NN, (long long)CC*NN, 48,
      DQ, (long long)NN*CC, CC, nullptr, nullptr, recl, nullptr, nullptr, nullptr, nullptr, (const float*)QS);
  // t = Wt*dq + bt -> T[o][n] f32, + BN partial sums
  gemm_k<0,0,5,4,4><<<dim3(24,2,8),256,0,stream>>>(WtH, DQ, 256, 256, 0, (long long)NN*CC, 4,
      nullptr, 0, 0, T, bt, nullptr, nullptr, nullptr, S1, S2, nullptr);
  bnfin_k<<<1,256,0,stream>>>(S1,S2,gamma,beta,scale,shift);
  outk<<<6144,256,0,stream>>>(T,q,scale,shift,out);
}

// Round 6
// 558.153 us; speedup vs baseline: 1.1997x; 1.0504x over previous
//
#include <hip/hip_runtime.h>

#define BB 8
#define CC 256
#define NN 3072

typedef unsigned short u16;
typedef unsigned int   u32;
typedef __attribute__((ext_vector_type(8))) __bf16 bf16x8;
typedef __attribute__((ext_vector_type(8))) u16    u16x8;
typedef __attribute__((ext_vector_type(4))) float  f32x4;

__device__ __forceinline__ float bf2f(u16 u){ u32 x=(u32)u<<16; return __builtin_bit_cast(float,x); }
__device__ __forceinline__ u16 f2bf(float f){ u32 i=__builtin_bit_cast(u32,f); i += 0x7FFFu + ((i>>16)&1u); return (u16)(i>>16); }
__device__ __forceinline__ u32 fkey(float f){ u32 u=__builtin_bit_cast(u32,f); return (u&0x80000000u)? ~u : (u|0x80000000u); }
__device__ __forceinline__ float funkey(u32 k){ u32 u=(k&0x80000000u)? (k^0x80000000u) : ~k; return __builtin_bit_cast(float,u); }

// async global->LDS, 16B per lane. LDS dest wave-uniform; HW adds lane*16.
__device__ __forceinline__ void gl_lds16(const u16* g, u16* l){
  __builtin_amdgcn_global_load_lds((const __attribute__((address_space(1))) void*)g,
                                   (__attribute__((address_space(3))) void*)l, 16, 0, 0);
}

// ---------------- prep: weight split (h,h,l over K'=768); Wq scaled by log2(e) ----------------
__global__ void prep_w(const float* __restrict__ Wq, const float* __restrict__ Wk,
                       const float* __restrict__ Wv, const float* __restrict__ Wt,
                       u16* __restrict__ WarrQ, u16* __restrict__ WarrK,
                       u16* __restrict__ WarrV, u16* __restrict__ WtH){
  int idx = blockIdx.x*256 + threadIdx.x;     // 4*65536
  int p = idx >> 16; int oc = idx & 65535; int o = oc >> 8; int c = oc & 255;
  const float* W = (p==0)?Wq:(p==1)?Wk:(p==2)?Wv:Wt;
  float v = W[oc];
  if(p==0) v *= 1.4426950408889634f;   // energies land in log2 domain -> v_exp_f32 is exp2
  u16 hi = f2bf(v);
  if(p==3){ WtH[oc]=hi; return; }
  u16 lo = f2bf(v - bf2f(hi));
  u16* dst = (p==0)?WarrQ:(p==1)?WarrK:WarrV;
  dst[(size_t)o*768 + c] = hi; dst[(size_t)o*768 + 256 + c] = hi; dst[(size_t)o*768 + 512 + c] = lo;
}

// ---------------- prep: transpose+split x,q -> [b][n][hi 256 | lo 256] ----------------
__global__ void prep_x(const float* __restrict__ x, const float* __restrict__ q,
                       u16* __restrict__ xs, u16* __restrict__ qs){
  int z=blockIdx.z, b=z&7, src=z>>3;
  const float* in = src? q : x;
  u16* outp = src? qs : xs;
  int n0=blockIdx.x*64, c0=blockIdx.y*64;
  __shared__ float t[64][65];
  int tid=threadIdx.x;
  {
    int r=tid>>2, nr=(tid&3)*16;
    const float* base = in + ((size_t)b*CC + c0 + r)*NN + n0 + nr;
    #pragma unroll
    for(int j=0;j<16;j+=4){
      f32x4 v = *(const f32x4*)(base + j);
      t[r][nr+j]=v[0]; t[r][nr+j+1]=v[1]; t[r][nr+j+2]=v[2]; t[r][nr+j+3]=v[3];
    }
  }
  __syncthreads();
  {
    int n=tid>>2, cw=(tid&3)*16;
    u16 hb[16] __attribute__((aligned(16)));
    u16 lb[16] __attribute__((aligned(16)));
    #pragma unroll
    for(int j=0;j<16;j++){
      float v=t[cw+j][n];
      u16 h=f2bf(v); hb[j]=h; lb[j]=f2bf(v-bf2f(h));
    }
    u16* ob = outp + ((size_t)b*NN + n0 + n)*512 + c0 + cw;
    *(u16x8*)(ob)       = *(const u16x8*)(hb);
    *(u16x8*)(ob+8)     = *(const u16x8*)(hb+8);
    *(u16x8*)(ob+256)   = *(const u16x8*)(lb);
    *(u16x8*)(ob+264)   = *(const u16x8*)(lb+8);
  }
}

// ---------------- the GEMM template ----------------
// C[M][N] = A[M][K'] * BT[N][K']^T, BK=64, 4 waves (2x2), 16x16x32 bf16 MFMA.
// Tile = 128 x (NW*32). Round-2 loop shape (best measured): runtime KT, per-iteration
// inline address calc, single-buffer LDS, vmcnt(0)+__syncthreads, bounds (256,2).
// [r3: explicit dbuf regressed @2.5 blk/CU; r4: bounds(256,4) spilled; r5: KTT unroll +
//  hoisted pointers regressed VGPR 80->92. Do not reintroduce.]
// DBUF=1 (PV only, 1 blk/CU -> no TLP): 2-deep pipeline, raw s_barrier + counted
// vmcnt(12); __syncthreads would drain vmcnt(0) and kill the prefetch.
// Staging: global_load_lds 16B, linear LDS dest + source-preswizzled chunk
// gc = slot ^ (row&7); reads apply the same XOR (both-sides-or-neither, rule #21).
template<int AMAP,int BMAP,int EPI,int NW,int DBUF>
__global__ __launch_bounds__(256,2)
void gemm_k(const u16* __restrict__ A, const u16* __restrict__ BT,
            int lda,int ldbt,long long sA,long long sB,int KT,
            u16* __restrict__ dst, long long sD, int lddst,
            float* __restrict__ dstF,
            const float* __restrict__ bias,
            const float* __restrict__ recl,
            u32* __restrict__ rmax,
            float* __restrict__ rsum,
            float* __restrict__ S1, float* __restrict__ S2,
            const float* __restrict__ qsrc)
{
  static_assert(!DBUF || NW==8, "vmcnt literal assumes 12 loads/tile");
  constexpr int BROWS = 2*NW*16;                   // B-tile rows (= C cols)
  constexpr int BCH   = BROWS/32;                  // B staging chunks
  constexpr int CORE  = 8192 + BROWS*64;           // As + Bs in u16
  constexpr int BASE  = (CORE > 17408 ? CORE : 17408);
  constexpr int SMSZ  = (DBUF ? 2*CORE : BASE) + 256;
  __shared__ u16 sm[SMSZ] __attribute__((aligned(16)));
  float* smax = (float*)(sm + BASE);
  const int tid=threadIdx.x, lane=tid&63, wave=tid>>6, wr=wave>>1, wc=wave&1;
  const int nt=blockIdx.x, mt=blockIdx.y, b=blockIdx.z;
  const int lr = lane>>4, lc = lane&15;

  if constexpr (EPI==3){ if(tid<128) smax[tid] = funkey(rmax[(size_t)b*NN + mt*128 + tid]); }

  f32x4 acc[4][NW];
  #pragma unroll
  for(int i=0;i<4;i++){
    #pragma unroll
    for(int j=0;j<NW;j++){ acc[i][j][0]=0.f; acc[i][j][1]=0.f; acc[i][j][2]=0.f; acc[i][j][3]=0.f; }
  }

  const u16* Ab = A + (size_t)b*sA + (size_t)mt*128*lda;
  const u16* Bb = BT + (size_t)b*sB + (size_t)nt*BROWS*ldbt;

  auto aoff=[&](int kt)->int{ int g=kt>>2,t4=(kt&3)*64;
    return t4 + (AMAP==0? g*256 : (AMAP==1? (g==2?256:0) : (g==1?256:0))); };
  auto boff=[&](int kt)->int{ int g=kt>>2,t4=(kt&3)*64;
    return t4 + (BMAP==0? g*256 : (BMAP==1? (g==2?256:0) : (g==1?256:0))); };

  auto stage=[&](int p,int ao,int bo){
    #pragma unroll
    for(int i=0;i<4;i++){
      int f=i*256+tid, row=f>>3, gc=(f&7)^(row&7);
      gl_lds16(Ab + (size_t)row*lda + ao + gc*8, sm + p*CORE + (i*256 + wave*64)*8);
    }
    #pragma unroll
    for(int i=0;i<BCH;i++){
      int f=i*256+tid, row=f>>3, gc=(f&7)^(row&7);
      gl_lds16(Bb + (size_t)row*ldbt + bo + gc*8, sm + p*CORE + 8192 + (i*256 + wave*64)*8);
    }
  };
  auto compute=[&](int p){
    const u16* As = sm + p*CORE;
    const u16* Bs = As + 8192;
    #pragma unroll
    for(int kk=0;kk<2;kk++){
      bf16x8 af[4], bfv[NW];
      int c0 = kk*4 + lr;
      #pragma unroll
      for(int i=0;i<4;i++){
        int row = wr*64 + i*16 + lc;
        af[i]  = *(const bf16x8*)(As + (size_t)row*64 + ((c0^(row&7))*8));
      }
      #pragma unroll
      for(int j=0;j<NW;j++){
        int row = wc*(NW*16) + j*16 + lc;
        bfv[j] = *(const bf16x8*)(Bs + (size_t)row*64 + ((c0^(row&7))*8));
      }
      #pragma unroll
      for(int i=0;i<4;i++){
        #pragma unroll
        for(int j=0;j<NW;j++)
          acc[i][j] = __builtin_amdgcn_mfma_f32_16x16x32_bf16(af[i], bfv[j], acc[i][j], 0,0,0);
      }
    }
  };

  if constexpr (DBUF){
    stage(0, aoff(0), boff(0));
    for(int kt=0; kt<KT; ++kt){
      int cur = kt&1;
      if(kt+1<KT){
        stage(cur^1, aoff(kt+1), boff(kt+1));
        asm volatile("s_waitcnt vmcnt(12)" ::: "memory");   // wait current tile only
      } else {
        asm volatile("s_waitcnt vmcnt(0)" ::: "memory");
      }
      __builtin_amdgcn_s_barrier();
      __builtin_amdgcn_sched_barrier(0);
      compute(cur);
      __builtin_amdgcn_sched_barrier(0);
      __builtin_amdgcn_s_barrier();
    }
  } else {
    for(int kt=0; kt<KT; ++kt){
      if(kt) __syncthreads();
      stage(0, aoff(kt), boff(kt));
      asm volatile("s_waitcnt vmcnt(0)" ::: "memory");
      __syncthreads();
      compute(0);
    }
  }

  const int rbase = mt*128 + wr*64;
  const int cbase = nt*BROWS + wc*(NW*16);

  if constexpr (EPI==0){
    // hi/lo split write via LDS coalesce: round 0 = hi, round 1 = lo
    u16* D = dst + (size_t)b*sD;
    u16* Pb = sm;   // [128][136]
    #pragma unroll
    for(int half=0; half<2; ++half){
      __syncthreads();
      #pragma unroll
      for(int i=0;i<4;i++){
        #pragma unroll
        for(int r=0;r<4;r++){
          int rl = wr*64 + i*16 + lr*4 + r;
          #pragma unroll
          for(int j=0;j<NW;j++){
            float v = acc[i][j][r];
            u16 h = f2bf(v);
            Pb[rl*136 + wc*(NW*16) + j*16 + lc] = half ? f2bf(v - bf2f(h)) : h;
          }
        }
      }
      __syncthreads();
      #pragma unroll
      for(int it=0; it<8; ++it){
        int ch = it*256 + tid, row = ch>>4, ccol=(ch&15)*8;
        *(u16x8*)(D + (size_t)(mt*128+row)*lddst + half*256 + nt*128 + ccol)
            = *(const u16x8*)(Pb + row*136 + ccol);
      }
    }
  } else if constexpr (EPI==1){
    u16* D = dst + (size_t)b*sD;
    #pragma unroll
    for(int i=0;i<4;i++){
      #pragma unroll
      for(int r=0;r<4;r++){
        int row = rbase + i*16 + lr*4 + r;
        float bv_ = bias[row];
        #pragma unroll
        for(int j=0;j<NW;j++){
          int col = cbase + j*16 + lc;
          D[(size_t)row*lddst + col] = f2bf(acc[i][j][r] + bv_);
        }
      }
    }
  } else if constexpr (EPI==2){
    #pragma unroll
    for(int i=0;i<4;i++){
      #pragma unroll
      for(int r=0;r<4;r++){
        float mx = acc[i][0][r];
        #pragma unroll
        for(int j=1;j<NW;j++) mx = fmaxf(mx, acc[i][j][r]);
        mx = fmaxf(mx, __shfl_xor(mx,1));
        mx = fmaxf(mx, __shfl_xor(mx,2));
        mx = fmaxf(mx, __shfl_xor(mx,4));
        mx = fmaxf(mx, __shfl_xor(mx,8));
        if(lc==0){
          int row = rbase + i*16 + lr*4 + r;
          atomicMax(&rmax[(size_t)b*NN + row], fkey(mx));
        }
      }
    }
  } else if constexpr (EPI==3){
    __syncthreads();
    u16* Pb = sm;   // [128][136] overlay (reads of As/Bs all done)
    #pragma unroll
    for(int i=0;i<4;i++){
      #pragma unroll
      for(int r=0;r<4;r++){
        int rl = wr*64 + i*16 + lr*4 + r;
        float mx = smax[rl];
        float s=0.f;
        #pragma unroll
        for(int j=0;j<NW;j++){
          float e2 = acc[i][j][r] - mx;   // log2-domain
          float p;
          asm("v_exp_f32 %0, %1" : "=v"(p) : "v"(e2));
          s+=p;
          Pb[rl*136 + wc*(NW*16) + j*16 + lc] = f2bf(p);
        }
        s += __shfl_xor(s,1); s += __shfl_xor(s,2); s += __shfl_xor(s,4); s += __shfl_xor(s,8);
        if(lc==0) atomicAdd(&rsum[(size_t)b*NN + mt*128 + rl], s);
      }
    }
    __syncthreads();
    u16* D = dst + (size_t)b*sD;
    #pragma unroll
    for(int it=0; it<8; ++it){
      int ch = it*256 + tid, row = ch>>4, ccol=(ch&15)*8;
      *(u16x8*)(D + (size_t)(mt*128+row)*lddst + nt*128 + ccol) = *(const u16x8*)(Pb + row*136 + ccol);
    }
  } else if constexpr (EPI==4){
    const float* rl_ = recl + (size_t)b*NN;
    const u16* qs_b  = (const u16*)qsrc + (size_t)b*NN*512;   // q split [n][hi|lo]
    u16* D = dst + (size_t)b*sD;
    #pragma unroll
    for(int i=0;i<4;i++){
      int nb = rbase + i*16 + lr*4;
      float rc[4];
      #pragma unroll
      for(int r=0;r<4;r++) rc[r] = rl_[nb+r];
      #pragma unroll
      for(int j=0;j<NW;j++){
        int c_ = cbase + j*16 + lc;
        #pragma unroll
        for(int r=0;r<4;r++){
          const u16* qr = qs_b + (size_t)(nb+r)*512 + c_;
          float qv = bf2f(qr[0]) + bf2f(qr[256]);
          float dq = qv - acc[i][j][r]*rc[r];
          D[(size_t)(nb+r)*lddst + c_] = f2bf(dq);
        }
      }
    }
  } else if constexpr (EPI==5){
    float* Df = dstF + (size_t)b*CC*NN;
    #pragma unroll
    for(int i=0;i<4;i++){
      #pragma unroll
      for(int r=0;r<4;r++){
        int row = rbase + i*16 + lr*4 + r;
        float bt_ = bias[row];
        float s=0.f, s2=0.f;
        #pragma unroll
        for(int j=0;j<NW;j++){
          int col = cbase + j*16 + lc;
          float v = acc[i][j][r] + bt_;
          Df[(size_t)row*NN + col] = v;
          s += v; s2 += v*v;
        }
        s  += __shfl_xor(s,1);  s  += __shfl_xor(s,2);  s  += __shfl_xor(s,4);  s  += __shfl_xor(s,8);
        s2 += __shfl_xor(s2,1); s2 += __shfl_xor(s2,2); s2 += __shfl_xor(s2,4); s2 += __shfl_xor(s2,8);
        if(lc==0){ atomicAdd(&S1[row], s); atomicAdd(&S2[row], s2); }
      }
    }
  }
}

// ---------------- small kernels ----------------
__global__ void recl_k(const float* __restrict__ l, float* __restrict__ recl){
  int i = blockIdx.x*256 + threadIdx.x;  // 24576
  recl[i] = 1.0f / l[i];
}

// colsum[m] = sum_n P[n][m] * recl[n], vectorized 8 cols / thread (16B loads)
__global__ void colsum_k(const u16* __restrict__ P, const float* __restrict__ recl,
                         float* __restrict__ colsum){
  int b = blockIdx.z;
  int m0 = blockIdx.x*1024 + threadIdx.x*8;  // gridDim.x=3, blockDim=128
  int n0 = blockIdx.y*48;                    // gridDim.y=64
  const u16* Pb = P + (size_t)b*NN*NN;
  const float* rb = recl + (size_t)b*NN;
  float acc[8] = {0,0,0,0,0,0,0,0};
  for(int i=0;i<48;i++){
    int n = n0+i;
    u16x8 v = *(const u16x8*)(Pb + (size_t)n*NN + m0);
    float r = rb[n];
    #pragma unroll
    for(int j=0;j<8;j++) acc[j] += bf2f(v[j]) * r;
  }
  float* cb = colsum + (size_t)b*NN + m0;
  #pragma unroll
  for(int j=0;j<8;j++) atomicAdd(&cb[j], acc[j]);
}

__global__ void vprime_k(const u16* __restrict__ XV, const float* __restrict__ colsum,
                         u16* __restrict__ VpT){
  size_t base = ((size_t)blockIdx.x*256 + threadIdx.x)*8;   // grid 3072
  int m = (int)(base % NN);
  int b = (int)(base / ((size_t)NN*CC));
  const float* cs = colsum + (size_t)b*NN + m;
  u16x8 v = *(const u16x8*)(XV + base);
  u16x8 o;
  #pragma unroll
  for(int j=0;j<8;j++) o[j] = f2bf(bf2f(v[j]) / (1e-9f + cs[j]));
  *(u16x8*)(VpT + base) = o;
}

__global__ void bnfin_k(const float* __restrict__ S1, const float* __restrict__ S2,
                        const float* __restrict__ gamma, const float* __restrict__ beta,
                        float* __restrict__ scale, float* __restrict__ shift){
  int c = threadIdx.x;
  float cnt = (float)(BB*NN);
  float mean = S1[c]/cnt;
  float var  = S2[c]/cnt - mean*mean;
  float rs = rsqrtf(var + 1e-5f);
  float sc = gamma[c]*rs;
  scale[c] = sc;
  shift[c] = beta[c] - mean*sc;
}

__global__ void outk(const float* __restrict__ T, const float* __restrict__ q,
                     const float* __restrict__ scale, const float* __restrict__ shift,
                     float* __restrict__ out){
  size_t i4 = (size_t)blockIdx.x*256 + threadIdx.x;    // 1,572,864 float4's
  int c = (int)((i4 / 768) & 255);
  f32x4 tv = *(const f32x4*)(T + i4*4);
  f32x4 qv = *(const f32x4*)(q + i4*4);
  float sc = scale[c], sh = shift[c];
  f32x4 o;
  #pragma unroll
  for(int k=0;k<4;k++){
    float h = tv[k]*sc + sh;
    o[k] = qv[k] + (h>0.f? h : 0.f);
  }
  *(f32x4*)(out + i4*4) = o;
}

// ---------------- launcher ----------------
extern "C" void kernel_launch(void* const* d_in, const int* in_sizes, int n_in,
                              void* d_out, int out_size, void* d_ws, size_t ws_size,
                              hipStream_t stream)
{
  const float* x  = (const float*)d_in[0];
  const float* q  = (const float*)d_in[1];
  const float* Wq = (const float*)d_in[2];
  const float* Wk = (const float*)d_in[3];
  const float* Wv = (const float*)d_in[4];
  const float* bv = (const float*)d_in[5];
  const float* Wt = (const float*)d_in[6];
  const float* bt = (const float*)d_in[7];
  const float* gamma=(const float*)d_in[8];
  const float* beta =(const float*)d_in[9];
  float* out = (float*)d_out;
  char* ws = (char*)d_ws;

  u16* P    = (u16*)(ws + 0);            // 150,994,944
  u16* XQ   = (u16*)(ws + 150994944);    // 25,165,824  (VpT aliases after vprime)
  u16* XK   = (u16*)(ws + 176160768);    // 25,165,824
  u16* QS   = (u16*)(ws + 201326592);    // 25,165,824  (T aliases after PV)
  u16* XS   = (u16*)(ws + 226492416);    // 25,165,824  (DQ aliases after PV)
  u16* XV   = (u16*)(ws + 251658240);    // 12,582,912
  u16* WarrQ= (u16*)(ws + 264241152);
  u16* WarrK= (u16*)(ws + 264634368);
  u16* WarrV= (u16*)(ws + 265027584);
  u16* WtH  = (u16*)(ws + 265420800);
  u32* rmax = (u32*)(ws + 265551872);
  float* l  = (float*)(ws + 265551872 + 98304);
  float* colsum=(float*)(ws + 265551872 + 196608);
  float* S1 = (float*)(ws + 265551872 + 294912);
  float* S2 = (float*)(ws + 265551872 + 295936);
  float* recl = (float*)(ws + 265848832);
  float* scale= (float*)(ws + 265947136);
  float* shift= (float*)(ws + 265948160);
  u16* VpT = XQ;
  float* T = (float*)QS;
  u16* DQ  = XS;

  hipMemsetAsync(ws + 265551872, 0, 296960, stream);

  prep_w<<<1024,256,0,stream>>>(Wq,Wk,Wv,Wt,WarrQ,WarrK,WarrV,WtH);
  prep_x<<<dim3(48,4,16),256,0,stream>>>(x,q,XS,QS);

  // x_q = (log2e*Wq)*q (split K'=768) -> XQ[n][hi|lo]
  gemm_k<2,0,0,4,0><<<dim3(2,24,8),256,0,stream>>>(QS, WarrQ, 512, 768, (long long)NN*512, 0, 12,
      XQ, (long long)NN*512, 512, nullptr, nullptr, nullptr, nullptr, nullptr, nullptr, nullptr, nullptr);
  // x_k = Wk*x -> XK[m][hi|lo]
  gemm_k<2,0,0,4,0><<<dim3(2,24,8),256,0,stream>>>(XS, WarrK, 512, 768, (long long)NN*512, 0, 12,
      XK, (long long)NN*512, 512, nullptr, nullptr, nullptr, nullptr, nullptr, nullptr, nullptr, nullptr);
  // x_v = Wv*x + bv -> XV[c][m]
  gemm_k<0,2,1,4,0><<<dim3(24,2,8),256,0,stream>>>(WarrV, XS, 768, 512, 0, (long long)NN*512, 12,
      XV, (long long)CC*NN, NN, nullptr, bv, nullptr, nullptr, nullptr, nullptr, nullptr, nullptr);
  // approx rowmax (hi*hi only, first 768 columns; underestimate-safe shift)
  gemm_k<0,0,2,4,0><<<dim3(6,24,8),256,0,stream>>>(XQ, XK, 512, 512, (long long)NN*512, (long long)NN*512, 4,
      nullptr, 0, 0, nullptr, nullptr, nullptr, rmax, nullptr, nullptr, nullptr, nullptr);
  // split energy -> P = exp2(e2 - m2), rowsums l
  gemm_k<1,2,3,4,0><<<dim3(24,24,8),256,0,stream>>>(XQ, XK, 512, 512, (long long)NN*512, (long long)NN*512, 12,
      P, (long long)NN*NN, NN, nullptr, nullptr, nullptr, rmax, l, nullptr, nullptr, nullptr);
  recl_k<<<96,256,0,stream>>>(l, recl);
  colsum_k<<<dim3(3,64,8),128,0,stream>>>(P, recl, colsum);
  vprime_k<<<3072,256,0,stream>>>(XV, colsum, VpT);
  // x_r^T, fused dq = q - x_r -> DQ[n][c]  (128x256 tile, P read once, 2-deep raw-barrier pipeline)
  gemm_k<0,0,4,8,1><<<dim3(1,24,8),256,0,stream>>>(P, VpT, NN, NN, (long long)NN*NN, (long long)CC*NN, 48,
      DQ, (long long)NN*CC, CC, nullptr, nullptr, recl, nullptr, nullptr, nullptr, nullptr, (const float*)QS);
  // t = Wt*dq + bt -> T[o][n] f32, + BN partial sums
  gemm_k<0,0,5,4,0><<<dim3(24,2,8),256,0,stream>>>(WtH, DQ, 256, 256, 0, (long long)NN*CC, 4,
      nullptr, 0, 0, T, bt, nullptr, nullptr, nullptr, S1, S2, nullptr);
  bnfin_k<<<1,256,0,stream>>>(S1,S2,gamma,beta,scale,shift);
  outk<<<6144,256,0,stream>>>(T,q,scale,shift,out);
}

// Round 9
// 467.657 us; speedup vs baseline: 1.4318x; 1.1935x over previous
//
#include <hip/hip_runtime.h>

#define BB 8
#define CC 256
#define NN 3072

typedef unsigned short u16;
typedef unsigned int   u32;
typedef __attribute__((ext_vector_type(8))) __bf16    bf16x8;
typedef __attribute__((ext_vector_type(8))) _Float16  h16x8;
typedef __attribute__((ext_vector_type(8))) u16       u16x8;
typedef __attribute__((ext_vector_type(4))) float     f32x4;

__device__ __forceinline__ float bf2f(u16 u){ u32 x=(u32)u<<16; return __builtin_bit_cast(float,x); }
__device__ __forceinline__ u16 f2bf(float f){ u32 i=__builtin_bit_cast(u32,f); i += 0x7FFFu + ((i>>16)&1u); return (u16)(i>>16); }
__device__ __forceinline__ u16 f2h(float f){ _Float16 h=(_Float16)f; return __builtin_bit_cast(u16,h); }

// async global->LDS, 16B per lane. LDS dest wave-uniform; HW adds lane*16.
__device__ __forceinline__ void gl_lds16(const u16* g, u16* l){
  __builtin_amdgcn_global_load_lds((const __attribute__((address_space(1))) void*)g,
                                   (__attribute__((address_space(3))) void*)l, 16, 0, 0);
}

// ---------------- prep: weight split (h,h,l over K'=768); Wq scaled by log2(e) ----------------
__global__ void prep_w(const float* __restrict__ Wq, const float* __restrict__ Wk,
                       const float* __restrict__ Wv, const float* __restrict__ Wt,
                       u16* __restrict__ WarrQ, u16* __restrict__ WarrK,
                       u16* __restrict__ WarrV, u16* __restrict__ WtH){
  int idx = blockIdx.x*256 + threadIdx.x;     // 4*65536
  int p = idx >> 16; int oc = idx & 65535; int o = oc >> 8; int c = oc & 255;
  const float* W = (p==0)?Wq:(p==1)?Wk:(p==2)?Wv:Wt;
  float v = W[oc];
  if(p==0) v *= 1.4426950408889634f;   // energies land in log2 domain -> v_exp_f32 is exp2
  u16 hi = f2bf(v);
  if(p==3){ WtH[oc]=hi; return; }
  u16 lo = f2bf(v - bf2f(hi));
  u16* dst = (p==0)?WarrQ:(p==1)?WarrK:WarrV;
  dst[(size_t)o*768 + c] = hi; dst[(size_t)o*768 + 256 + c] = hi; dst[(size_t)o*768 + 512 + c] = lo;
}

// ---------------- prep: transpose+split x,q -> [b][n][hi 256 | lo 256] ----------------
__global__ void prep_x(const float* __restrict__ x, const float* __restrict__ q,
                       u16* __restrict__ xs, u16* __restrict__ qs){
  int z=blockIdx.z, b=z&7, src=z>>3;
  const float* in = src? q : x;
  u16* outp = src? qs : xs;
  int n0=blockIdx.x*64, c0=blockIdx.y*64;
  __shared__ float t[64][65];
  int tid=threadIdx.x;
  {
    int r=tid>>2, nr=(tid&3)*16;
    const float* base = in + ((size_t)b*CC + c0 + r)*NN + n0 + nr;
    #pragma unroll
    for(int j=0;j<16;j+=4){
      f32x4 v = *(const f32x4*)(base + j);
      t[r][nr+j]=v[0]; t[r][nr+j+1]=v[1]; t[r][nr+j+2]=v[2]; t[r][nr+j+3]=v[3];
    }
  }
  __syncthreads();
  {
    int n=tid>>2, cw=(tid&3)*16;
    u16 hb[16] __attribute__((aligned(16)));
    u16 lb[16] __attribute__((aligned(16)));
    #pragma unroll
    for(int j=0;j<16;j++){
      float v=t[cw+j][n];
      u16 h=f2bf(v); hb[j]=h; lb[j]=f2bf(v-bf2f(h));
    }
    u16* ob = outp + ((size_t)b*NN + n0 + n)*512 + c0 + cw;
    *(u16x8*)(ob)       = *(const u16x8*)(hb);
    *(u16x8*)(ob+8)     = *(const u16x8*)(hb+8);
    *(u16x8*)(ob+256)   = *(const u16x8*)(lb);
    *(u16x8*)(ob+264)   = *(const u16x8*)(lb+8);
  }
}

// ---------------- the GEMM template ----------------
// C[M][N] = A[M][K'] * BT[N][K']^T, BK=64, 4 waves (2x2), 16x16x32 MFMA, DT: 0=bf16 1=fp16.
// Tile = 128 x (NW*32). Round-2 loop shape (best measured): runtime KT, per-iteration
// inline address calc, single-buffer LDS, vmcnt(0)+__syncthreads, bounds (256,2).
// [r3: explicit dbuf regressed @2.5 blk/CU; r4: bounds(256,4) spilled; r5: KTT unroll +
//  hoisted pointers regressed VGPR 80->92. Do not reintroduce.]
// DBUF=1 (PV only, 1 blk/CU -> no TLP): 2-deep pipeline, raw s_barrier + counted
// vmcnt(12); __syncthreads would drain vmcnt(0) and kill the prefetch.
// Staging: global_load_lds 16B, linear LDS dest + source-preswizzled chunk
// gc = slot ^ (row&7); reads apply the same XOR (both-sides-or-neither, rule #21).
// EPI: 1=+bias bf16 direct; 3=P=exp2(acc-64)+rowsum (fixed shift: max e2 ~ 141 < 191,
//      shift cancels in P/l); 4=dq=q-x_r; 5=+bias bf16 write + BN partials; 6=fp16
//      LDS-coalesced write.
template<int AMAP,int BMAP,int EPI,int NW,int DBUF,int DT>
__global__ __launch_bounds__(256,2)
void gemm_k(const u16* __restrict__ A, const u16* __restrict__ BT,
            int lda,int ldbt,long long sA,long long sB,int KT,
            u16* __restrict__ dst, long long sD, int lddst,
            const float* __restrict__ bias,
            const float* __restrict__ recl,
            float* __restrict__ rsum,
            float* __restrict__ S1, float* __restrict__ S2,
            const float* __restrict__ qsrc)
{
  static_assert(!DBUF || NW==8, "vmcnt literal assumes 12 loads/tile");
  constexpr int BROWS = 2*NW*16;                   // B-tile rows (= C cols)
  constexpr int BCH   = BROWS/32;                  // B staging chunks
  constexpr int CORE  = 8192 + BROWS*64;           // As + Bs in u16
  constexpr int BASE  = (CORE > 17408 ? CORE : 17408);
  constexpr int SMSZ  = (DBUF ? 2*CORE : BASE) + 256;
  __shared__ u16 sm[SMSZ] __attribute__((aligned(16)));
  const int tid=threadIdx.x, lane=tid&63, wave=tid>>6, wr=wave>>1, wc=wave&1;
  const int nt=blockIdx.x, mt=blockIdx.y, b=blockIdx.z;
  const int lr = lane>>4, lc = lane&15;

  f32x4 acc[4][NW];
  #pragma unroll
  for(int i=0;i<4;i++){
    #pragma unroll
    for(int j=0;j<NW;j++){ acc[i][j][0]=0.f; acc[i][j][1]=0.f; acc[i][j][2]=0.f; acc[i][j][3]=0.f; }
  }

  const u16* Ab = A + (size_t)b*sA + (size_t)mt*128*lda;
  const u16* Bb = BT + (size_t)b*sB + (size_t)nt*BROWS*ldbt;

  auto aoff=[&](int kt)->int{ int g=kt>>2,t4=(kt&3)*64;
    return t4 + (AMAP==0? g*256 : (AMAP==1? (g==2?256:0) : (g==1?256:0))); };
  auto boff=[&](int kt)->int{ int g=kt>>2,t4=(kt&3)*64;
    return t4 + (BMAP==0? g*256 : (BMAP==1? (g==2?256:0) : (g==1?256:0))); };

  auto stage=[&](int p,int ao,int bo){
    #pragma unroll
    for(int i=0;i<4;i++){
      int f=i*256+tid, row=f>>3, gc=(f&7)^(row&7);
      gl_lds16(Ab + (size_t)row*lda + ao + gc*8, sm + p*CORE + (i*256 + wave*64)*8);
    }
    #pragma unroll
    for(int i=0;i<BCH;i++){
      int f=i*256+tid, row=f>>3, gc=(f&7)^(row&7);
      gl_lds16(Bb + (size_t)row*ldbt + bo + gc*8, sm + p*CORE + 8192 + (i*256 + wave*64)*8);
    }
  };
  auto compute=[&](int p){
    const u16* As = sm + p*CORE;
    const u16* Bs = As + 8192;
    #pragma unroll
    for(int kk=0;kk<2;kk++){
      int c0 = kk*4 + lr;
      if constexpr (DT==0){
        bf16x8 af[4], bfv[NW];
        #pragma unroll
        for(int i=0;i<4;i++){
          int row = wr*64 + i*16 + lc;
          af[i]  = *(const bf16x8*)(As + (size_t)row*64 + ((c0^(row&7))*8));
        }
        #pragma unroll
        for(int j=0;j<NW;j++){
          int row = wc*(NW*16) + j*16 + lc;
          bfv[j] = *(const bf16x8*)(Bs + (size_t)row*64 + ((c0^(row&7))*8));
        }
        #pragma unroll
        for(int i=0;i<4;i++){
          #pragma unroll
          for(int j=0;j<NW;j++)
            acc[i][j] = __builtin_amdgcn_mfma_f32_16x16x32_bf16(af[i], bfv[j], acc[i][j], 0,0,0);
        }
      } else {
        h16x8 af[4], bfv[NW];
        #pragma unroll
        for(int i=0;i<4;i++){
          int row = wr*64 + i*16 + lc;
          af[i]  = *(const h16x8*)(As + (size_t)row*64 + ((c0^(row&7))*8));
        }
        #pragma unroll
        for(int j=0;j<NW;j++){
          int row = wc*(NW*16) + j*16 + lc;
          bfv[j] = *(const h16x8*)(Bs + (size_t)row*64 + ((c0^(row&7))*8));
        }
        #pragma unroll
        for(int i=0;i<4;i++){
          #pragma unroll
          for(int j=0;j<NW;j++)
            acc[i][j] = __builtin_amdgcn_mfma_f32_16x16x32_f16(af[i], bfv[j], acc[i][j], 0,0,0);
        }
      }
    }
  };

  if constexpr (DBUF){
    stage(0, aoff(0), boff(0));
    for(int kt=0; kt<KT; ++kt){
      int cur = kt&1;
      if(kt+1<KT){
        stage(cur^1, aoff(kt+1), boff(kt+1));
        asm volatile("s_waitcnt vmcnt(12)" ::: "memory");   // wait current tile only
      } else {
        asm volatile("s_waitcnt vmcnt(0)" ::: "memory");
      }
      __builtin_amdgcn_s_barrier();
      __builtin_amdgcn_sched_barrier(0);
      compute(cur);
      __builtin_amdgcn_sched_barrier(0);
      __builtin_amdgcn_s_barrier();
    }
  } else {
    for(int kt=0; kt<KT; ++kt){
      if(kt) __syncthreads();
      stage(0, aoff(kt), boff(kt));
      asm volatile("s_waitcnt vmcnt(0)" ::: "memory");
      __syncthreads();
      compute(0);
    }
  }

  const int rbase = mt*128 + wr*64;
  const int cbase = nt*BROWS + wc*(NW*16);

  if constexpr (EPI==1){
    u16* D = dst + (size_t)b*sD;
    #pragma unroll
    for(int i=0;i<4;i++){
      #pragma unroll
      for(int r=0;r<4;r++){
        int row = rbase + i*16 + lr*4 + r;
        float bv_ = bias[row];
        #pragma unroll
        for(int j=0;j<NW;j++){
          int col = cbase + j*16 + lc;
          D[(size_t)row*lddst + col] = f2bf(acc[i][j][r] + bv_);
        }
      }
    }
  } else if constexpr (EPI==3){
    __syncthreads();
    u16* Pb = sm;   // [128][136] overlay (reads of As/Bs all done)
    #pragma unroll
    for(int i=0;i<4;i++){
      #pragma unroll
      for(int r=0;r<4;r++){
        int rl = wr*64 + i*16 + lr*4 + r;
        float s=0.f;
        #pragma unroll
        for(int j=0;j<NW;j++){
          float e2 = acc[i][j][r] - 64.0f;   // fixed shift, log2-domain
          float p;
          asm("v_exp_f32 %0, %1" : "=v"(p) : "v"(e2));
          s+=p;
          Pb[rl*136 + wc*(NW*16) + j*16 + lc] = f2bf(p);
        }
        s += __shfl_xor(s,1); s += __shfl_xor(s,2); s += __shfl_xor(s,4); s += __shfl_xor(s,8);
        if(lc==0) atomicAdd(&rsum[(size_t)b*NN + mt*128 + rl], s);
      }
    }
    __syncthreads();
    u16* D = dst + (size_t)b*sD;
    #pragma unroll
    for(int it=0; it<8; ++it){
      int ch = it*256 + tid, row = ch>>4, ccol=(ch&15)*8;
      *(u16x8*)(D + (size_t)(mt*128+row)*lddst + nt*128 + ccol) = *(const u16x8*)(Pb + row*136 + ccol);
    }
  } else if constexpr (EPI==4){
    const float* rl_ = recl + (size_t)b*NN;
    const u16* qs_b  = (const u16*)qsrc + (size_t)b*NN*512;   // q split [n][hi|lo]
    u16* D = dst + (size_t)b*sD;
    #pragma unroll
    for(int i=0;i<4;i++){
      int nb = rbase + i*16 + lr*4;
      float rc[4];
      #pragma unroll
      for(int r=0;r<4;r++) rc[r] = rl_[nb+r];
      #pragma unroll
      for(int j=0;j<NW;j++){
        int c_ = cbase + j*16 + lc;
        #pragma unroll
        for(int r=0;r<4;r++){
          const u16* qr = qs_b + (size_t)(nb+r)*512 + c_;
          float qv = bf2f(qr[0]) + bf2f(qr[256]);
          float dq = qv - acc[i][j][r]*rc[r];
          D[(size_t)(nb+r)*lddst + c_] = f2bf(dq);
        }
      }
    }
  } else if constexpr (EPI==5){
    u16* D = dst + (size_t)b*sD;
    #pragma unroll
    for(int i=0;i<4;i++){
      #pragma unroll
      for(int r=0;r<4;r++){
        int row = rbase + i*16 + lr*4 + r;
        float bt_ = bias[row];
        float s=0.f, s2=0.f;
        #pragma unroll
        for(int j=0;j<NW;j++){
          int col = cbase + j*16 + lc;
          float v = acc[i][j][r] + bt_;
          D[(size_t)row*lddst + col] = f2bf(v);
          s += v; s2 += v*v;
        }
        s  += __shfl_xor(s,1);  s  += __shfl_xor(s,2);  s  += __shfl_xor(s,4);  s  += __shfl_xor(s,8);
        s2 += __shfl_xor(s2,1); s2 += __shfl_xor(s2,2); s2 += __shfl_xor(s2,4); s2 += __shfl_xor(s2,8);
        if(lc==0){ atomicAdd(&S1[row], s); atomicAdd(&S2[row], s2); }
      }
    }
  } else if constexpr (EPI==6){
    // fp16 single write via LDS coalesce
    __syncthreads();
    u16* Pb = sm;   // [128][136]
    #pragma unroll
    for(int i=0;i<4;i++){
      #pragma unroll
      for(int r=0;r<4;r++){
        int rl = wr*64 + i*16 + lr*4 + r;
        #pragma unroll
        for(int j=0;j<NW;j++){
          Pb[rl*136 + wc*(NW*16) + j*16 + lc] = f2h(acc[i][j][r]);
        }
      }
    }
    __syncthreads();
    u16* D = dst + (size_t)b*sD;
    #pragma unroll
    for(int it=0; it<8; ++it){
      int ch = it*256 + tid, row = ch>>4, ccol=(ch&15)*8;
      *(u16x8*)(D + (size_t)(mt*128+row)*lddst + nt*128 + ccol) = *(const u16x8*)(Pb + row*136 + ccol);
    }
  }
}

// ---------------- small kernels ----------------
__global__ void recl_k(const float* __restrict__ l, float* __restrict__ recl){
  int i = blockIdx.x*256 + threadIdx.x;  // 24576
  recl[i] = 1.0f / l[i];
}

// colsum[m] = sum_n P[n][m] * recl[n], vectorized 8 cols / thread (16B loads)
__global__ void colsum_k(const u16* __restrict__ P, const float* __restrict__ recl,
                         float* __restrict__ colsum){
  int b = blockIdx.z;
  int m0 = blockIdx.x*1024 + threadIdx.x*8;  // gridDim.x=3, blockDim=128
  int n0 = blockIdx.y*48;                    // gridDim.y=64
  const u16* Pb = P + (size_t)b*NN*NN;
  const float* rb = recl + (size_t)b*NN;
  float acc[8] = {0,0,0,0,0,0,0,0};
  for(int i=0;i<48;i++){
    int n = n0+i;
    u16x8 v = *(const u16x8*)(Pb + (size_t)n*NN + m0);
    float r = rb[n];
    #pragma unroll
    for(int j=0;j<8;j++) acc[j] += bf2f(v[j]) * r;
  }
  float* cb = colsum + (size_t)b*NN + m0;
  #pragma unroll
  for(int j=0;j<8;j++) atomicAdd(&cb[j], acc[j]);
}

__global__ void vprime_k(const u16* __restrict__ XV, const float* __restrict__ colsum,
                         u16* __restrict__ VpT){
  size_t base = ((size_t)blockIdx.x*256 + threadIdx.x)*8;   // grid 3072
  int m = (int)(base % NN);
  int b = (int)(base / ((size_t)NN*CC));
  const float* cs = colsum + (size_t)b*NN + m;
  u16x8 v = *(const u16x8*)(XV + base);
  u16x8 o;
  #pragma unroll
  for(int j=0;j<8;j++) o[j] = f2bf(bf2f(v[j]) / (1e-9f + cs[j]));
  *(u16x8*)(VpT + base) = o;
}

__global__ void bnfin_k(const float* __restrict__ S1, const float* __restrict__ S2,
                        const float* __restrict__ gamma, const float* __restrict__ beta,
                        float* __restrict__ scale, float* __restrict__ shift){
  int c = threadIdx.x;
  float cnt = (float)(BB*NN);
  float mean = S1[c]/cnt;
  float var  = S2[c]/cnt - mean*mean;
  float rs = rsqrtf(var + 1e-5f);
  float sc = gamma[c]*rs;
  scale[c] = sc;
  shift[c] = beta[c] - mean*sc;
}

__global__ void outk(const u16* __restrict__ T, const float* __restrict__ q,
                     const float* __restrict__ scale, const float* __restrict__ shift,
                     float* __restrict__ out){
  size_t base = ((size_t)blockIdx.x*256 + threadIdx.x)*8;   // 6,291,456 elems, grid 3072
  int c = (int)((base / NN) & 255);
  u16x8 tv = *(const u16x8*)(T + base);
  f32x4 q0 = *(const f32x4*)(q + base);
  f32x4 q1 = *(const f32x4*)(q + base + 4);
  float sc = scale[c], sh = shift[c];
  f32x4 o0, o1;
  #pragma unroll
  for(int k=0;k<4;k++){
    float h0 = bf2f(tv[k])*sc + sh;
    float h1 = bf2f(tv[4+k])*sc + sh;
    o0[k] = q0[k] + (h0>0.f? h0 : 0.f);
    o1[k] = q1[k] + (h1>0.f? h1 : 0.f);
  }
  *(f32x4*)(out + base)     = o0;
  *(f32x4*)(out + base + 4) = o1;
}

// ---------------- launcher ----------------
extern "C" void kernel_launch(void* const* d_in, const int* in_sizes, int n_in,
                              void* d_out, int out_size, void* d_ws, size_t ws_size,
                              hipStream_t stream)
{
  const float* x  = (const float*)d_in[0];
  const float* q  = (const float*)d_in[1];
  const float* Wq = (const float*)d_in[2];
  const float* Wk = (const float*)d_in[3];
  const float* Wv = (const float*)d_in[4];
  const float* bv = (const float*)d_in[5];
  const float* Wt = (const float*)d_in[6];
  const float* bt = (const float*)d_in[7];
  const float* gamma=(const float*)d_in[8];
  const float* beta =(const float*)d_in[9];
  float* out = (float*)d_out;
  char* ws = (char*)d_ws;

  u16* P    = (u16*)(ws + 0);            // 150,994,944  bf16 [b][n][m]
  u16* XQH  = (u16*)(ws + 150994944);    // 12,582,912   fp16 [b][n][256]
  u16* XKH  = (u16*)(ws + 163577856);    // 12,582,912   fp16 [b][m][256]
  u16* QS   = (u16*)(ws + 176160768);    // 25,165,824   split q (T bf16 aliases after PV)
  u16* XS   = (u16*)(ws + 201326592);    // 25,165,824   split x
  u16* XV   = (u16*)(ws + 226492416);    // 12,582,912   bf16 [b][c][m]
  u16* VpT  = (u16*)(ws + 239075328);    // 12,582,912   bf16 [b][c][m]
  u16* DQ   = (u16*)(ws + 251658240);    // 12,582,912   bf16 [b][n][c]
  u16* WarrQ= (u16*)(ws + 264241152);
  u16* WarrK= (u16*)(ws + 264634368);
  u16* WarrV= (u16*)(ws + 265027584);
  u16* WtH  = (u16*)(ws + 265420800);
  float* l     = (float*)(ws + 265551872);
  float* colsum= (float*)(ws + 265650176);
  float* S1    = (float*)(ws + 265748480);
  float* S2    = (float*)(ws + 265749504);
  float* recl  = (float*)(ws + 265750528);
  float* scale = (float*)(ws + 265848832);
  float* shift = (float*)(ws + 265849856);
  u16* T = QS;   // bf16 [b][o][n], written after last QS read (PV)

  hipMemsetAsync(ws + 265551872, 0, 198656, stream);   // l, colsum, S1, S2

  prep_w<<<1024,256,0,stream>>>(Wq,Wk,Wv,Wt,WarrQ,WarrK,WarrV,WtH);
  prep_x<<<dim3(48,4,16),256,0,stream>>>(x,q,XS,QS);

  // x_q = (log2e*Wq)*q (split K'=768, f32 acc) -> fp16 XQH[n][256]
  gemm_k<2,0,6,4,0,0><<<dim3(2,24,8),256,0,stream>>>(QS, WarrQ, 512, 768, (long long)NN*512, 0, 12,
      XQH, (long long)NN*256, 256, nullptr, nullptr, nullptr, nullptr, nullptr, nullptr);
  // x_k = Wk*x -> fp16 XKH[m][256]
  gemm_k<2,0,6,4,0,0><<<dim3(2,24,8),256,0,stream>>>(XS, WarrK, 512, 768, (long long)NN*512, 0, 12,
      XKH, (long long)NN*256, 256, nullptr, nullptr, nullptr, nullptr, nullptr, nullptr);
  // x_v = Wv*x + bv -> XV[c][m] bf16
  gemm_k<0,2,1,4,0,0><<<dim3(24,2,8),256,0,stream>>>(WarrV, XS, 768, 512, 0, (long long)NN*512, 12,
      XV, (long long)CC*NN, NN, bv, nullptr, nullptr, nullptr, nullptr, nullptr);
  // energy (single fp16 pass, K=256) -> P = exp2(e2 - 64), rowsums l
  gemm_k<0,0,3,4,0,1><<<dim3(24,24,8),256,0,stream>>>(XQH, XKH, 256, 256, (long long)NN*256, (long long)NN*256, 4,
      P, (long long)NN*NN, NN, nullptr, nullptr, l, nullptr, nullptr, nullptr);
  recl_k<<<96,256,0,stream>>>(l, recl);
  colsum_k<<<dim3(3,64,8),128,0,stream>>>(P, recl, colsum);
  vprime_k<<<3072,256,0,stream>>>(XV, colsum, VpT);
  // x_r^T, fused dq = q - x_r -> DQ[n][c]  (128x256 tile, P read once, 2-deep raw-barrier pipeline)
  gemm_k<0,0,4,8,1,0><<<dim3(1,24,8),256,0,stream>>>(P, VpT, NN, NN, (long long)NN*NN, (long long)CC*NN, 48,
      DQ, (long long)NN*CC, CC, nullptr, recl, nullptr, nullptr, nullptr, (const float*)QS);
  // t = Wt*dq + bt -> T[o][n] bf16, + BN partial sums
  gemm_k<0,0,5,4,0,0><<<dim3(24,2,8),256,0,stream>>>(WtH, DQ, 256, 256, 0, (long long)NN*CC, 4,
      T, (long long)CC*NN, NN, bt, nullptr, nullptr, S1, S2, nullptr);
  bnfin_k<<<1,256,0,stream>>>(S1,S2,gamma,beta,scale,shift);
  outk<<<3072,256,0,stream>>>(T,q,scale,shift,out);
}

// Round 12
// 459.696 us; speedup vs baseline: 1.4566x; 1.0173x over previous
//
#include <hip/hip_runtime.h>

#define BB 8
#define CC 256
#define NN 3072

typedef unsigned short u16;
typedef unsigned int   u32;
typedef __attribute__((ext_vector_type(8))) __bf16    bf16x8;
typedef __attribute__((ext_vector_type(8))) _Float16  h16x8;
typedef __attribute__((ext_vector_type(8))) u16       u16x8;
typedef __attribute__((ext_vector_type(4))) float     f32x4;

__device__ __forceinline__ float bf2f(u16 u){ u32 x=(u32)u<<16; return __builtin_bit_cast(float,x); }
__device__ __forceinline__ u16 f2bf(float f){ u32 i=__builtin_bit_cast(u32,f); i += 0x7FFFu + ((i>>16)&1u); return (u16)(i>>16); }
__device__ __forceinline__ u16 f2h(float f){ _Float16 h=(_Float16)f; return __builtin_bit_cast(u16,h); }

// async global->LDS, 16B per lane. LDS dest wave-uniform; HW adds lane*16.
__device__ __forceinline__ void gl_lds16(const u16* g, u16* l){
  __builtin_amdgcn_global_load_lds((const __attribute__((address_space(1))) void*)g,
                                   (__attribute__((address_space(3))) void*)l, 16, 0, 0);
}

// ---------------- prep: weight split (h,h,l over K'=768); Wq scaled by log2(e) ----------------
__global__ void prep_w(const float* __restrict__ Wq, const float* __restrict__ Wk,
                       const float* __restrict__ Wv, const float* __restrict__ Wt,
                       u16* __restrict__ WarrQ, u16* __restrict__ WarrK,
                       u16* __restrict__ WarrV, u16* __restrict__ WtH){
  int idx = blockIdx.x*256 + threadIdx.x;     // 4*65536
  int p = idx >> 16; int oc = idx & 65535; int o = oc >> 8; int c = oc & 255;
  const float* W = (p==0)?Wq:(p==1)?Wk:(p==2)?Wv:Wt;
  float v = W[oc];
  if(p==0) v *= 1.4426950408889634f;   // energies land in log2 domain -> v_exp_f32 is exp2
  u16 hi = f2bf(v);
  if(p==3){ WtH[oc]=hi; return; }
  u16 lo = f2bf(v - bf2f(hi));
  u16* dst = (p==0)?WarrQ:(p==1)?WarrK:WarrV;
  dst[(size_t)o*768 + c] = hi; dst[(size_t)o*768 + 256 + c] = hi; dst[(size_t)o*768 + 512 + c] = lo;
}

// ---------------- prep: transpose+split x,q -> [b][n][hi 256 | lo 256] ----------------
__global__ void prep_x(const float* __restrict__ x, const float* __restrict__ q,
                       u16* __restrict__ xs, u16* __restrict__ qs){
  int z=blockIdx.z, b=z&7, src=z>>3;
  const float* in = src? q : x;
  u16* outp = src? qs : xs;
  int n0=blockIdx.x*64, c0=blockIdx.y*64;
  __shared__ float t[64][65];
  int tid=threadIdx.x;
  {
    int r=tid>>2, nr=(tid&3)*16;
    const float* base = in + ((size_t)b*CC + c0 + r)*NN + n0 + nr;
    #pragma unroll
    for(int j=0;j<16;j+=4){
      f32x4 v = *(const f32x4*)(base + j);
      t[r][nr+j]=v[0]; t[r][nr+j+1]=v[1]; t[r][nr+j+2]=v[2]; t[r][nr+j+3]=v[3];
    }
  }
  __syncthreads();
  {
    int n=tid>>2, cw=(tid&3)*16;
    u16 hb[16] __attribute__((aligned(16)));
    u16 lb[16] __attribute__((aligned(16)));
    #pragma unroll
    for(int j=0;j<16;j++){
      float v=t[cw+j][n];
      u16 h=f2bf(v); hb[j]=h; lb[j]=f2bf(v-bf2f(h));
    }
    u16* ob = outp + ((size_t)b*NN + n0 + n)*512 + c0 + cw;
    *(u16x8*)(ob)       = *(const u16x8*)(hb);
    *(u16x8*)(ob+8)     = *(const u16x8*)(hb+8);
    *(u16x8*)(ob+256)   = *(const u16x8*)(lb);
    *(u16x8*)(ob+264)   = *(const u16x8*)(lb+8);
  }
}

// ---------------- the GEMM body ----------------
// C[M][N] = A[M][K'] * BT[N][K']^T, BK=64, 4 waves (2x2), 16x16x32 MFMA, DT: 0=bf16 1=fp16.
// Tile = 128 x (NW*32). Round-2 loop shape (best measured): runtime KT, per-iteration
// inline address calc, single-buffer LDS, vmcnt(0)+__syncthreads.
// Launch bounds live on thin __global__ wrappers (gemm_k3 = (256,3) for NW=4:
//   VGPR 76 + AGPR 64 = 140 <= 168 @ 3 waves/EU; gemm_k2 = (256,2) for DBUF NW=8).
// [r3: explicit dbuf regressed @2.5 blk/CU; r4: bounds(256,4) spilled; r5: KTT unroll +
//  hoisted pointers regressed VGPR 80->92. Do not reintroduce.]
// DBUF=1 (PV only, 1 blk/CU -> no TLP): 2-deep pipeline, raw s_barrier + counted
// vmcnt(12); __syncthreads would drain vmcnt(0) and kill the prefetch.
// Staging: global_load_lds 16B, linear LDS dest + source-preswizzled chunk
// gc = slot ^ (row&7); reads apply the same XOR (both-sides-or-neither, rule #21).
// EPI: 1=+bias bf16 direct; 3=P=exp2(acc-64)+rowsum (fixed shift: max e2 ~ 141 < 191,
//      shift cancels in P/l); 4=dq=q-x_r; 5=+bias bf16 write + BN partials; 6=fp16
//      LDS-coalesced write.
template<int AMAP,int BMAP,int EPI,int NW,int DBUF,int DT>
__device__ __forceinline__
void gemm_body(const u16* __restrict__ A, const u16* __restrict__ BT,
               int lda,int ldbt,long long sA,long long sB,int KT,
               u16* __restrict__ dst, long long sD, int lddst,
               const float* __restrict__ bias,
               const float* __restrict__ recl,
               float* __restrict__ rsum,
               float* __restrict__ S1, float* __restrict__ S2,
               const float* __restrict__ qsrc)
{
  static_assert(!DBUF || NW==8, "vmcnt literal assumes 12 loads/tile");
  constexpr int BROWS = 2*NW*16;                   // B-tile rows (= C cols)
  constexpr int BCH   = BROWS/32;                  // B staging chunks
  constexpr int CORE  = 8192 + BROWS*64;           // As + Bs in u16
  constexpr int BASE  = (CORE > 17408 ? CORE : 17408);
  constexpr int SMSZ  = (DBUF ? 2*CORE : BASE) + 256;
  __shared__ u16 sm[SMSZ] __attribute__((aligned(16)));
  const int tid=threadIdx.x, lane=tid&63, wave=tid>>6, wr=wave>>1, wc=wave&1;
  const int nt=blockIdx.x, mt=blockIdx.y, b=blockIdx.z;
  const int lr = lane>>4, lc = lane&15;

  f32x4 acc[4][NW];
  #pragma unroll
  for(int i=0;i<4;i++){
    #pragma unroll
    for(int j=0;j<NW;j++){ acc[i][j][0]=0.f; acc[i][j][1]=0.f; acc[i][j][2]=0.f; acc[i][j][3]=0.f; }
  }

  const u16* Ab = A + (size_t)b*sA + (size_t)mt*128*lda;
  const u16* Bb = BT + (size_t)b*sB + (size_t)nt*BROWS*ldbt;

  auto aoff=[&](int kt)->int{ int g=kt>>2,t4=(kt&3)*64;
    return t4 + (AMAP==0? g*256 : (AMAP==1? (g==2?256:0) : (g==1?256:0))); };
  auto boff=[&](int kt)->int{ int g=kt>>2,t4=(kt&3)*64;
    return t4 + (BMAP==0? g*256 : (BMAP==1? (g==2?256:0) : (g==1?256:0))); };

  auto stage=[&](int p,int ao,int bo){
    #pragma unroll
    for(int i=0;i<4;i++){
      int f=i*256+tid, row=f>>3, gc=(f&7)^(row&7);
      gl_lds16(Ab + (size_t)row*lda + ao + gc*8, sm + p*CORE + (i*256 + wave*64)*8);
    }
    #pragma unroll
    for(int i=0;i<BCH;i++){
      int f=i*256+tid, row=f>>3, gc=(f&7)^(row&7);
      gl_lds16(Bb + (size_t)row*ldbt + bo + gc*8, sm + p*CORE + 8192 + (i*256 + wave*64)*8);
    }
  };
  auto compute=[&](int p){
    const u16* As = sm + p*CORE;
    const u16* Bs = As + 8192;
    #pragma unroll
    for(int kk=0;kk<2;kk++){
      int c0 = kk*4 + lr;
      if constexpr (DT==0){
        bf16x8 af[4], bfv[NW];
        #pragma unroll
        for(int i=0;i<4;i++){
          int row = wr*64 + i*16 + lc;
          af[i]  = *(const bf16x8*)(As + (size_t)row*64 + ((c0^(row&7))*8));
        }
        #pragma unroll
        for(int j=0;j<NW;j++){
          int row = wc*(NW*16) + j*16 + lc;
          bfv[j] = *(const bf16x8*)(Bs + (size_t)row*64 + ((c0^(row&7))*8));
        }
        #pragma unroll
        for(int i=0;i<4;i++){
          #pragma unroll
          for(int j=0;j<NW;j++)
            acc[i][j] = __builtin_amdgcn_mfma_f32_16x16x32_bf16(af[i], bfv[j], acc[i][j], 0,0,0);
        }
      } else {
        h16x8 af[4], bfv[NW];
        #pragma unroll
        for(int i=0;i<4;i++){
          int row = wr*64 + i*16 + lc;
          af[i]  = *(const h16x8*)(As + (size_t)row*64 + ((c0^(row&7))*8));
        }
        #pragma unroll
        for(int j=0;j<NW;j++){
          int row = wc*(NW*16) + j*16 + lc;
          bfv[j] = *(const h16x8*)(Bs + (size_t)row*64 + ((c0^(row&7))*8));
        }
        #pragma unroll
        for(int i=0;i<4;i++){
          #pragma unroll
          for(int j=0;j<NW;j++)
            acc[i][j] = __builtin_amdgcn_mfma_f32_16x16x32_f16(af[i], bfv[j], acc[i][j], 0,0,0);
        }
      }
    }
  };

  if constexpr (DBUF){
    stage(0, aoff(0), boff(0));
    for(int kt=0; kt<KT; ++kt){
      int cur = kt&1;
      if(kt+1<KT){
        stage(cur^1, aoff(kt+1), boff(kt+1));
        asm volatile("s_waitcnt vmcnt(12)" ::: "memory");   // wait current tile only
      } else {
        asm volatile("s_waitcnt vmcnt(0)" ::: "memory");
      }
      __builtin_amdgcn_s_barrier();
      __builtin_amdgcn_sched_barrier(0);
      compute(cur);
      __builtin_amdgcn_sched_barrier(0);
      __builtin_amdgcn_s_barrier();
    }
  } else {
    for(int kt=0; kt<KT; ++kt){
      if(kt) __syncthreads();
      stage(0, aoff(kt), boff(kt));
      asm volatile("s_waitcnt vmcnt(0)" ::: "memory");
      __syncthreads();
      compute(0);
    }
  }

  const int rbase = mt*128 + wr*64;
  const int cbase = nt*BROWS + wc*(NW*16);

  if constexpr (EPI==1){
    u16* D = dst + (size_t)b*sD;
    #pragma unroll
    for(int i=0;i<4;i++){
      #pragma unroll
      for(int r=0;r<4;r++){
        int row = rbase + i*16 + lr*4 + r;
        float bv_ = bias[row];
        #pragma unroll
        for(int j=0;j<NW;j++){
          int col = cbase + j*16 + lc;
          D[(size_t)row*lddst + col] = f2bf(acc[i][j][r] + bv_);
        }
      }
    }
  } else if constexpr (EPI==3){
    __syncthreads();
    u16* Pb = sm;   // [128][136] overlay (reads of As/Bs all done)
    #pragma unroll
    for(int i=0;i<4;i++){
      #pragma unroll
      for(int r=0;r<4;r++){
        int rl = wr*64 + i*16 + lr*4 + r;
        float s=0.f;
        #pragma unroll
        for(int j=0;j<NW;j++){
          float e2 = acc[i][j][r] - 64.0f;   // fixed shift, log2-domain
          float p;
          asm("v_exp_f32 %0, %1" : "=v"(p) : "v"(e2));
          s+=p;
          Pb[rl*136 + wc*(NW*16) + j*16 + lc] = f2bf(p);
        }
        s += __shfl_xor(s,1); s += __shfl_xor(s,2); s += __shfl_xor(s,4); s += __shfl_xor(s,8);
        if(lc==0) atomicAdd(&rsum[(size_t)b*NN + mt*128 + rl], s);
      }
    }
    __syncthreads();
    u16* D = dst + (size_t)b*sD;
    #pragma unroll
    for(int it=0; it<8; ++it){
      int ch = it*256 + tid, row = ch>>4, ccol=(ch&15)*8;
      *(u16x8*)(D + (size_t)(mt*128+row)*lddst + nt*128 + ccol) = *(const u16x8*)(Pb + row*136 + ccol);
    }
  } else if constexpr (EPI==4){
    const float* rl_ = recl + (size_t)b*NN;
    const u16* qs_b  = (const u16*)qsrc + (size_t)b*NN*512;   // q split [n][hi|lo]
    u16* D = dst + (size_t)b*sD;
    #pragma unroll
    for(int i=0;i<4;i++){
      int nb = rbase + i*16 + lr*4;
      float rc[4];
      #pragma unroll
      for(int r=0;r<4;r++) rc[r] = rl_[nb+r];
      #pragma unroll
      for(int j=0;j<NW;j++){
        int c_ = cbase + j*16 + lc;
        #pragma unroll
        for(int r=0;r<4;r++){
          const u16* qr = qs_b + (size_t)(nb+r)*512 + c_;
          float qv = bf2f(qr[0]) + bf2f(qr[256]);
          float dq = qv - acc[i][j][r]*rc[r];
          D[(size_t)(nb+r)*lddst + c_] = f2bf(dq);
        }
      }
    }
  } else if constexpr (EPI==5){
    u16* D = dst + (size_t)b*sD;
    #pragma unroll
    for(int i=0;i<4;i++){
      #pragma unroll
      for(int r=0;r<4;r++){
        int row = rbase + i*16 + lr*4 + r;
        float bt_ = bias[row];
        float s=0.f, s2=0.f;
        #pragma unroll
        for(int j=0;j<NW;j++){
          int col = cbase + j*16 + lc;
          float v = acc[i][j][r] + bt_;
          D[(size_t)row*lddst + col] = f2bf(v);
          s += v; s2 += v*v;
        }
        s  += __shfl_xor(s,1);  s  += __shfl_xor(s,2);  s  += __shfl_xor(s,4);  s  += __shfl_xor(s,8);
        s2 += __shfl_xor(s2,1); s2 += __shfl_xor(s2,2); s2 += __shfl_xor(s2,4); s2 += __shfl_xor(s2,8);
        if(lc==0){ atomicAdd(&S1[row], s); atomicAdd(&S2[row], s2); }
      }
    }
  } else if constexpr (EPI==6){
    // fp16 single write via LDS coalesce
    __syncthreads();
    u16* Pb = sm;   // [128][136]
    #pragma unroll
    for(int i=0;i<4;i++){
      #pragma unroll
      for(int r=0;r<4;r++){
        int rl = wr*64 + i*16 + lr*4 + r;
        #pragma unroll
        for(int j=0;j<NW;j++){
          Pb[rl*136 + wc*(NW*16) + j*16 + lc] = f2h(acc[i][j][r]);
        }
      }
    }
    __syncthreads();
    u16* D = dst + (size_t)b*sD;
    #pragma unroll
    for(int it=0; it<8; ++it){
      int ch = it*256 + tid, row = ch>>4, ccol=(ch&15)*8;
      *(u16x8*)(D + (size_t)(mt*128+row)*lddst + nt*128 + ccol) = *(const u16x8*)(Pb + row*136 + ccol);
    }
  }
}

// thin wrappers: literal launch bounds (template-dependent bounds suspected in r10/r11 fails)
template<int AMAP,int BMAP,int EPI,int NW,int DBUF,int DT>
__global__ __launch_bounds__(256,3)
void gemm_k3(const u16* __restrict__ A, const u16* __restrict__ BT,
             int lda,int ldbt,long long sA,long long sB,int KT,
             u16* __restrict__ dst, long long sD, int lddst,
             const float* __restrict__ bias, const float* __restrict__ recl,
             float* __restrict__ rsum, float* __restrict__ S1, float* __restrict__ S2,
             const float* __restrict__ qsrc){
  gemm_body<AMAP,BMAP,EPI,NW,DBUF,DT>(A,BT,lda,ldbt,sA,sB,KT,dst,sD,lddst,bias,recl,rsum,S1,S2,qsrc);
}

template<int AMAP,int BMAP,int EPI,int NW,int DBUF,int DT>
__global__ __launch_bounds__(256,2)
void gemm_k2(const u16* __restrict__ A, const u16* __restrict__ BT,
             int lda,int ldbt,long long sA,long long sB,int KT,
             u16* __restrict__ dst, long long sD, int lddst,
             const float* __restrict__ bias, const float* __restrict__ recl,
             float* __restrict__ rsum, float* __restrict__ S1, float* __restrict__ S2,
             const float* __restrict__ qsrc){
  gemm_body<AMAP,BMAP,EPI,NW,DBUF,DT>(A,BT,lda,ldbt,sA,sB,KT,dst,sD,lddst,bias,recl,rsum,S1,S2,qsrc);
}

// ---------------- small kernels ----------------
__global__ void recl_k(const float* __restrict__ l, float* __restrict__ recl){
  int i = blockIdx.x*256 + threadIdx.x;  // 24576
  recl[i] = 1.0f / l[i];
}

// colsum[m] = sum_n P[n][m] * recl[n], vectorized 8 cols / thread (16B loads)
__global__ void colsum_k(const u16* __restrict__ P, const float* __restrict__ recl,
                         float* __restrict__ colsum){
  int b = blockIdx.z;
  int m0 = blockIdx.x*1024 + threadIdx.x*8;  // gridDim.x=3, blockDim=128
  int n0 = blockIdx.y*48;                    // gridDim.y=64
  const u16* Pb = P + (size_t)b*NN*NN;
  const float* rb = recl + (size_t)b*NN;
  float acc[8] = {0,0,0,0,0,0,0,0};
  for(int i=0;i<48;i++){
    int n = n0+i;
    u16x8 v = *(const u16x8*)(Pb + (size_t)n*NN + m0);
    float r = rb[n];
    #pragma unroll
    for(int j=0;j<8;j++) acc[j] += bf2f(v[j]) * r;
  }
  float* cb = colsum + (size_t)b*NN + m0;
  #pragma unroll
  for(int j=0;j<8;j++) atomicAdd(&cb[j], acc[j]);
}

__global__ void vprime_k(const u16* __restrict__ XV, const float* __restrict__ colsum,
                         u16* __restrict__ VpT){
  size_t base = ((size_t)blockIdx.x*256 + threadIdx.x)*8;   // grid 3072
  int m = (int)(base % NN);
  int b = (int)(base / ((size_t)NN*CC));
  const float* cs = colsum + (size_t)b*NN + m;
  u16x8 v = *(const u16x8*)(XV + base);
  u16x8 o;
  #pragma unroll
  for(int j=0;j<8;j++) o[j] = f2bf(bf2f(v[j]) / (1e-9f + cs[j]));
  *(u16x8*)(VpT + base) = o;
}

__global__ void bnfin_k(const float* __restrict__ S1, const float* __restrict__ S2,
                        const float* __restrict__ gamma, const float* __restrict__ beta,
                        float* __restrict__ scale, float* __restrict__ shift){
  int c = threadIdx.x;
  float cnt = (float)(BB*NN);
  float mean = S1[c]/cnt;
  float var  = S2[c]/cnt - mean*mean;
  float rs = rsqrtf(var + 1e-5f);
  float sc = gamma[c]*rs;
  scale[c] = sc;
  shift[c] = beta[c] - mean*sc;
}

__global__ void outk(const u16* __restrict__ T, const float* __restrict__ q,
                     const float* __restrict__ scale, const float* __restrict__ shift,
                     float* __restrict__ out){
  size_t base = ((size_t)blockIdx.x*256 + threadIdx.x)*8;   // 6,291,456 elems, grid 3072
  int c = (int)((base / NN) & 255);
  u16x8 tv = *(const u16x8*)(T + base);
  f32x4 q0 = *(const f32x4*)(q + base);
  f32x4 q1 = *(const f32x4*)(q + base + 4);
  float sc = scale[c], sh = shift[c];
  f32x4 o0, o1;
  #pragma unroll
  for(int k=0;k<4;k++){
    float h0 = bf2f(tv[k])*sc + sh;
    float h1 = bf2f(tv[4+k])*sc + sh;
    o0[k] = q0[k] + (h0>0.f? h0 : 0.f);
    o1[k] = q1[k] + (h1>0.f? h1 : 0.f);
  }
  *(f32x4*)(out + base)     = o0;
  *(f32x4*)(out + base + 4) = o1;
}

// ---------------- launcher ----------------
extern "C" void kernel_launch(void* const* d_in, const int* in_sizes, int n_in,
                              void* d_out, int out_size, void* d_ws, size_t ws_size,
                              hipStream_t stream)
{
  const float* x  = (const float*)d_in[0];
  const float* q  = (const float*)d_in[1];
  const float* Wq = (const float*)d_in[2];
  const float* Wk = (const float*)d_in[3];
  const float* Wv = (const float*)d_in[4];
  const float* bv = (const float*)d_in[5];
  const float* Wt = (const float*)d_in[6];
  const float* bt = (const float*)d_in[7];
  const float* gamma=(const float*)d_in[8];
  const float* beta =(const float*)d_in[9];
  float* out = (float*)d_out;
  char* ws = (char*)d_ws;

  u16* P    = (u16*)(ws + 0);            // 150,994,944  bf16 [b][n][m]
  u16* XQH  = (u16*)(ws + 150994944);    // 12,582,912   fp16 [b][n][256]
  u16* XKH  = (u16*)(ws + 163577856);    // 12,582,912   fp16 [b][m][256]
  u16* QS   = (u16*)(ws + 176160768);    // 25,165,824   split q (T bf16 aliases after PV)
  u16* XS   = (u16*)(ws + 201326592);    // 25,165,824   split x
  u16* XV   = (u16*)(ws + 226492416);    // 12,582,912   bf16 [b][c][m]
  u16* VpT  = (u16*)(ws + 239075328);    // 12,582,912   bf16 [b][c][m]
  u16* DQ   = (u16*)(ws + 251658240);    // 12,582,912   bf16 [b][n][c]
  u16* WarrQ= (u16*)(ws + 264241152);
  u16* WarrK= (u16*)(ws + 264634368);
  u16* WarrV= (u16*)(ws + 265027584);
  u16* WtH  = (u16*)(ws + 265420800);
  float* l     = (float*)(ws + 265551872);
  float* colsum= (float*)(ws + 265650176);
  float* S1    = (float*)(ws + 265748480);
  float* S2    = (float*)(ws + 265749504);
  float* recl  = (float*)(ws + 265750528);
  float* scale = (float*)(ws + 265848832);
  float* shift = (float*)(ws + 265849856);
  u16* T = QS;   // bf16 [b][o][n], written after last QS read (PV)

  hipMemsetAsync(ws + 265551872, 0, 198656, stream);   // l, colsum, S1, S2

  prep_w<<<1024,256,0,stream>>>(Wq,Wk,Wv,Wt,WarrQ,WarrK,WarrV,WtH);
  prep_x<<<dim3(48,4,16),256,0,stream>>>(x,q,XS,QS);

  // x_q = (log2e*Wq)*q (split K'=768, f32 acc) -> fp16 XQH[n][256]
  gemm_k3<2,0,6,4,0,0><<<dim3(2,24,8),256,0,stream>>>(QS, WarrQ, 512, 768, (long long)NN*512, 0, 12,
      XQH, (long long)NN*256, 256, nullptr, nullptr, nullptr, nullptr, nullptr, nullptr);
  // x_k = Wk*x -> fp16 XKH[m][256]
  gemm_k3<2,0,6,4,0,0><<<dim3(2,24,8),256,0,stream>>>(XS, WarrK, 512, 768, (long long)NN*512, 0, 12,
      XKH, (long long)NN*256, 256, nullptr, nullptr, nullptr, nullptr, nullptr, nullptr);
  // x_v = Wv*x + bv -> XV[c][m] bf16
  gemm_k3<0,2,1,4,0,0><<<dim3(24,2,8),256,0,stream>>>(WarrV, XS, 768, 512, 0, (long long)NN*512, 12,
      XV, (long long)CC*NN, NN, bv, nullptr, nullptr, nullptr, nullptr, nullptr);
  // energy (single fp16 pass, K=256) -> P = exp2(e2 - 64), rowsums l
  gemm_k3<0,0,3,4,0,1><<<dim3(24,24,8),256,0,stream>>>(XQH, XKH, 256, 256, (long long)NN*256, (long long)NN*256, 4,
      P, (long long)NN*NN, NN, nullptr, nullptr, l, nullptr, nullptr, nullptr);
  recl_k<<<96,256,0,stream>>>(l, recl);
  colsum_k<<<dim3(3,64,8),128,0,stream>>>(P, recl, colsum);
  vprime_k<<<3072,256,0,stream>>>(XV, colsum, VpT);
  // x_r^T, fused dq = q - x_r -> DQ[n][c]  (128x256 tile, P read once, 2-deep raw-barrier pipeline)
  gemm_k2<0,0,4,8,1,0><<<dim3(1,24,8),256,0,stream>>>(P, VpT, NN, NN, (long long)NN*NN, (long long)CC*NN, 48,
      DQ, (long long)NN*CC, CC, nullptr, recl, nullptr, nullptr, nullptr, (const float*)QS);
  // t = Wt*dq + bt -> T[o][n] bf16, + BN partial sums
  gemm_k3<0,0,5,4,0,0><<<dim3(24,2,8),256,0,stream>>>(WtH, DQ, 256, 256, 0, (long long)NN*CC, 4,
      T, (long long)CC*NN, NN, bt, nullptr, nullptr, S1, S2, nullptr);
  bnfin_k<<<1,256,0,stream>>>(S1,S2,gamma,beta,scale,shift);
  outk<<<3072,256,0,stream>>>(T,q,scale,shift,out);
}